// Round 1
// baseline (1291.604 us; speedup 1.0000x reference)
//
#include <hip/hip_runtime.h>

#define N_EMBD 768
#define FULL   12288
#define KSEL   3072
#define BATCH  8
#define TLEN   1024
#define HID    48

// ---------------- pooled mean (deterministic 2-stage) ----------------
__global__ void pool_partial_kernel(const float* __restrict__ x, float* __restrict__ partial) {
  const int s = blockIdx.x;   // 0..15 (t-chunk of 64)
  const int b = blockIdx.y;   // 0..7
  const int tid = threadIdx.x;
  for (int d = tid; d < N_EMBD; d += 256) {
    float sum = 0.f;
    const float* base = x + ((size_t)b * TLEN + s * 64) * N_EMBD + d;
    #pragma unroll 4
    for (int t = 0; t < 64; ++t) sum += base[(size_t)t * N_EMBD];
    partial[(b * 16 + s) * N_EMBD + d] = sum;
  }
}

__global__ void pool_final_kernel(const float* __restrict__ partial, float* __restrict__ pooled) {
  const int b = blockIdx.x;
  const int tid = threadIdx.x;
  for (int d = tid; d < N_EMBD; d += 256) {
    float sum = 0.f;
    #pragma unroll
    for (int s = 0; s < 16; ++s) sum += partial[(b * 16 + s) * N_EMBD + d];
    pooled[b * N_EMBD + d] = sum * (1.f / TLEN);
  }
}

// ---------------- control net: ck = relu(pooled@w1^T)@w2^T ----------------
__global__ void control_kernel(const float* __restrict__ pooled, const float* __restrict__ w1,
                               const float* __restrict__ w2, float* __restrict__ ck) {
  const int b = blockIdx.x;
  const int tid = threadIdx.x;
  __shared__ float pool_s[N_EMBD];
  __shared__ float hid_s[HID];
  for (int d = tid; d < N_EMBD; d += 256) pool_s[d] = pooled[b * N_EMBD + d];
  __syncthreads();
  if (tid < HID) {
    float acc = 0.f;
    const float* wr = w1 + tid * N_EMBD;
    for (int d = 0; d < N_EMBD; ++d) acc = fmaf(pool_s[d], wr[d], acc);
    hid_s[tid] = fmaxf(acc, 0.f);
  }
  __syncthreads();
  for (int f = tid; f < FULL; f += 256) {
    const float* wr = w2 + (size_t)f * HID;
    float acc = 0.f;
    #pragma unroll
    for (int j = 0; j < HID; ++j) acc = fmaf(hid_s[j], wr[j], acc);
    ck[b * FULL + f] = acc;
  }
}

// ---------------- top-K selection (radix select, deterministic ties) ----------------
// softmax is monotone => top-K of softmax == top-K of ck. Ties broken by lowest index
// (matches jax.lax.top_k).
__global__ void topk_kernel(const float* __restrict__ ck, int* __restrict__ sel) {
  const int b = blockIdx.x;
  const int tid = threadIdx.x;
  __shared__ unsigned keys[FULL];        // 48 KB
  __shared__ unsigned red[256];
  __shared__ int sg[257], se[257];
  for (int f = tid; f < FULL; f += 256) {
    unsigned u = __float_as_uint(ck[b * FULL + f]);
    keys[f] = (u & 0x80000000u) ? ~u : (u | 0x80000000u);  // order-preserving map
  }
  __syncthreads();
  unsigned prefix = 0;
  int remaining = KSEL;
  const int f_lo = tid * (FULL / 256), f_hi = f_lo + (FULL / 256);
  for (int bit = 31; bit >= 0; --bit) {
    const unsigned want = prefix | (1u << bit);
    const unsigned shifted = want >> bit;
    unsigned cnt = 0;
    for (int f = f_lo; f < f_hi; ++f) cnt += ((keys[f] >> bit) == shifted) ? 1u : 0u;
    red[tid] = cnt;
    __syncthreads();
    for (int s = 128; s > 0; s >>= 1) {
      if (tid < s) red[tid] += red[tid + s];
      __syncthreads();
    }
    const int c = (int)red[0];
    __syncthreads();  // all read red[0] before next overwrite
    if (c >= remaining) prefix = want;
    else remaining -= c;
  }
  const unsigned kth = prefix;  // value of the K-th largest key
  int cg = 0, ce = 0;
  for (int f = f_lo; f < f_hi; ++f) { cg += (keys[f] > kth) ? 1 : 0; ce += (keys[f] == kth) ? 1 : 0; }
  sg[tid] = cg; se[tid] = ce;
  __syncthreads();
  if (tid == 0) {
    int ag = 0, ae = 0;
    for (int i = 0; i < 256; ++i) {
      int tg = sg[i], te = se[i];
      sg[i] = ag; se[i] = ae;
      ag += tg; ae += te;
    }
    sg[256] = ag;
  }
  __syncthreads();
  const int ng = sg[256];           // count strictly greater (< KSEL)
  int gpos = sg[tid], epos = se[tid];
  for (int f = f_lo; f < f_hi; ++f) {
    const unsigned k = keys[f];
    if (k > kth) {
      sel[b * KSEL + (gpos++)] = f;
    } else if (k == kth) {
      const int p = ng + epos;
      if (p < KSEL) sel[b * KSEL + p] = f;
      ++epos;
    }
  }
}

// ---------------- transpose w_proj (768 x 12288) -> wT (12288 x 768), once ----------------
__global__ void transpose_kernel(const float* __restrict__ wproj, float* __restrict__ wT) {
  __shared__ float tile[32][33];
  const int f0 = blockIdx.x * 32;
  const int e0 = blockIdx.y * 32;
  const int tx = threadIdx.x, ty = threadIdx.y;  // (32, 8)
  #pragma unroll
  for (int q = 0; q < 4; ++q)
    tile[ty + q * 8][tx] = wproj[(size_t)(e0 + ty + q * 8) * FULL + f0 + tx];
  __syncthreads();
  #pragma unroll
  for (int q = 0; q < 4; ++q)
    wT[(size_t)(f0 + ty + q * 8) * N_EMBD + e0 + tx] = tile[tx][ty + q * 8];
}

// ---------------- GEMM1: h[b] (1024 x 3072) = relu( X[b] (1024x768) @ gather(w_mfc, sel)^T ) ----
// tiles 128(t) x 128(f), K-step 16 over d; 256 threads, 8x8 micro-tile.
__global__ __launch_bounds__(256, 2) void gemm1_kernel(
    const float* __restrict__ x, const float* __restrict__ w_mfc,
    const int* __restrict__ sel, float* __restrict__ h) {
  const int b  = blockIdx.z;
  const int t0 = blockIdx.x * 128;
  const int f0 = blockIdx.y * 128;
  const int tid = threadIdx.x;
  __shared__ float As[16][132];  // As[k][i] = x[b][t0+i][d0+k]
  __shared__ float Bs[16][132];  // Bs[k][j] = w_mfc[sel[f0+j]][d0+k]
  const int r = tid >> 2, c = tid & 3;
  const float* xrow0 = x + ((size_t)b * TLEN + t0 + r) * N_EMBD;
  const float* xrow1 = xrow0 + (size_t)64 * N_EMBD;
  const int* selb = sel + b * KSEL;
  const float* wrow0 = w_mfc + (size_t)selb[f0 + r] * N_EMBD;
  const float* wrow1 = w_mfc + (size_t)selb[f0 + r + 64] * N_EMBD;
  const int tx = tid & 15, ty = tid >> 4;
  float acc[8][8];
  #pragma unroll
  for (int ii = 0; ii < 8; ++ii)
    #pragma unroll
    for (int jj = 0; jj < 8; ++jj) acc[ii][jj] = 0.f;

  for (int d0 = 0; d0 < N_EMBD; d0 += 16) {
    const float4 a0 = *(const float4*)(xrow0 + d0 + c * 4);
    const float4 a1 = *(const float4*)(xrow1 + d0 + c * 4);
    const float4 b0 = *(const float4*)(wrow0 + d0 + c * 4);
    const float4 b1 = *(const float4*)(wrow1 + d0 + c * 4);
    __syncthreads();
    As[c*4+0][r] = a0.x; As[c*4+1][r] = a0.y; As[c*4+2][r] = a0.z; As[c*4+3][r] = a0.w;
    As[c*4+0][r+64] = a1.x; As[c*4+1][r+64] = a1.y; As[c*4+2][r+64] = a1.z; As[c*4+3][r+64] = a1.w;
    Bs[c*4+0][r] = b0.x; Bs[c*4+1][r] = b0.y; Bs[c*4+2][r] = b0.z; Bs[c*4+3][r] = b0.w;
    Bs[c*4+0][r+64] = b1.x; Bs[c*4+1][r+64] = b1.y; Bs[c*4+2][r+64] = b1.z; Bs[c*4+3][r+64] = b1.w;
    __syncthreads();
    #pragma unroll
    for (int k = 0; k < 16; ++k) {
      const float4 av0 = *(const float4*)&As[k][ty * 4];
      const float4 av1 = *(const float4*)&As[k][ty * 4 + 64];
      const float4 bv0 = *(const float4*)&Bs[k][tx * 4];
      const float4 bv1 = *(const float4*)&Bs[k][tx * 4 + 64];
      const float a8[8] = {av0.x, av0.y, av0.z, av0.w, av1.x, av1.y, av1.z, av1.w};
      const float b8[8] = {bv0.x, bv0.y, bv0.z, bv0.w, bv1.x, bv1.y, bv1.z, bv1.w};
      #pragma unroll
      for (int ii = 0; ii < 8; ++ii)
        #pragma unroll
        for (int jj = 0; jj < 8; ++jj)
          acc[ii][jj] = fmaf(a8[ii], b8[jj], acc[ii][jj]);
    }
  }
  #pragma unroll
  for (int ii = 0; ii < 8; ++ii) {
    const int i = t0 + ty * 4 + ((ii < 4) ? ii : (64 + ii - 4));
    float* orow = h + ((size_t)b * TLEN + i) * KSEL + f0;
    float4 v0, v1;
    v0.x = fmaxf(acc[ii][0], 0.f); v0.y = fmaxf(acc[ii][1], 0.f);
    v0.z = fmaxf(acc[ii][2], 0.f); v0.w = fmaxf(acc[ii][3], 0.f);
    v1.x = fmaxf(acc[ii][4], 0.f); v1.y = fmaxf(acc[ii][5], 0.f);
    v1.z = fmaxf(acc[ii][6], 0.f); v1.w = fmaxf(acc[ii][7], 0.f);
    *(float4*)(orow + tx * 4) = v0;
    *(float4*)(orow + tx * 4 + 64) = v1;
  }
}

// ---------------- GEMM2: out[b] (1024 x 768) = h[b] (1024x3072) @ gather(wT, sel) ----------------
// tiles 128(t) x 64(e), K-step 16 over fc; 256 threads, 8x4 micro-tile.
__global__ __launch_bounds__(256, 3) void gemm2_kernel(
    const float* __restrict__ h, const float* __restrict__ wT,
    const int* __restrict__ sel, float* __restrict__ out) {
  const int b  = blockIdx.z;
  const int t0 = blockIdx.x * 128;
  const int e0 = blockIdx.y * 64;
  const int tid = threadIdx.x;
  __shared__ float As[16][132];  // As[k][i] = h[b][t0+i][k0+k]
  __shared__ float Bs[16][68];   // Bs[k][j] = wT[sel[k0+k]][e0+j]
  const int r = tid >> 2, c = tid & 3;
  const float* hrow0 = h + ((size_t)b * TLEN + t0 + r) * KSEL;
  const float* hrow1 = hrow0 + (size_t)64 * KSEL;
  const int kr = tid >> 4;   // 0..15 -> B tile row
  const int cc = tid & 15;   // float4 index within B row
  const int* selb = sel + b * KSEL;
  const int tx = tid & 15, ty = tid >> 4;
  float acc[8][4];
  #pragma unroll
  for (int ii = 0; ii < 8; ++ii)
    #pragma unroll
    for (int jj = 0; jj < 4; ++jj) acc[ii][jj] = 0.f;

  for (int k0 = 0; k0 < KSEL; k0 += 16) {
    const float4 a0 = *(const float4*)(hrow0 + k0 + c * 4);
    const float4 a1 = *(const float4*)(hrow1 + k0 + c * 4);
    const int sk = selb[k0 + kr];
    const float4 bv = *(const float4*)(wT + (size_t)sk * N_EMBD + e0 + cc * 4);
    __syncthreads();
    As[c*4+0][r] = a0.x; As[c*4+1][r] = a0.y; As[c*4+2][r] = a0.z; As[c*4+3][r] = a0.w;
    As[c*4+0][r+64] = a1.x; As[c*4+1][r+64] = a1.y; As[c*4+2][r+64] = a1.z; As[c*4+3][r+64] = a1.w;
    *(float4*)&Bs[kr][cc * 4] = bv;
    __syncthreads();
    #pragma unroll
    for (int k = 0; k < 16; ++k) {
      const float4 av0 = *(const float4*)&As[k][ty * 4];
      const float4 av1 = *(const float4*)&As[k][ty * 4 + 64];
      const float4 bq  = *(const float4*)&Bs[k][tx * 4];
      const float a8[8] = {av0.x, av0.y, av0.z, av0.w, av1.x, av1.y, av1.z, av1.w};
      const float b4[4] = {bq.x, bq.y, bq.z, bq.w};
      #pragma unroll
      for (int ii = 0; ii < 8; ++ii)
        #pragma unroll
        for (int jj = 0; jj < 4; ++jj)
          acc[ii][jj] = fmaf(a8[ii], b4[jj], acc[ii][jj]);
    }
  }
  #pragma unroll
  for (int ii = 0; ii < 8; ++ii) {
    const int i = t0 + ty * 4 + ((ii < 4) ? ii : (64 + ii - 4));
    float4 v;
    v.x = acc[ii][0]; v.y = acc[ii][1]; v.z = acc[ii][2]; v.w = acc[ii][3];
    *(float4*)(out + ((size_t)b * TLEN + i) * N_EMBD + e0 + tx * 4) = v;
  }
}

// ---------------- launch ----------------
extern "C" void kernel_launch(void* const* d_in, const int* in_sizes, int n_in,
                              void* d_out, int out_size, void* d_ws, size_t ws_size,
                              hipStream_t stream) {
  const float* x      = (const float*)d_in[0];
  const float* w1     = (const float*)d_in[1];
  const float* w2     = (const float*)d_in[2];
  const float* w_mfc  = (const float*)d_in[3];
  const float* w_proj = (const float*)d_in[4];
  float* out = (float*)d_out;

  char* ws = (char*)d_ws;
  size_t off = 0;
  auto alloc = [&](size_t bytes) -> void* {
    void* p = ws + off;
    off += (bytes + 255) & ~(size_t)255;
    return p;
  };
  float* partial = (float*)alloc((size_t)BATCH * 16 * N_EMBD * 4);
  float* pooled  = (float*)alloc((size_t)BATCH * N_EMBD * 4);
  float* ckbuf   = (float*)alloc((size_t)BATCH * FULL * 4);
  int*   sel     = (int*)  alloc((size_t)BATCH * KSEL * 4);
  float* wT      = (float*)alloc((size_t)FULL * N_EMBD * 4);
  float* h       = (float*)alloc((size_t)BATCH * TLEN * KSEL * 4);

  // one-time transpose of w_proj (independent of control path)
  transpose_kernel<<<dim3(FULL / 32, N_EMBD / 32), dim3(32, 8), 0, stream>>>(w_proj, wT);
  // control path
  pool_partial_kernel<<<dim3(16, BATCH), 256, 0, stream>>>(x, partial);
  pool_final_kernel<<<BATCH, 256, 0, stream>>>(partial, pooled);
  control_kernel<<<BATCH, 256, 0, stream>>>(pooled, w1, w2, ckbuf);
  topk_kernel<<<BATCH, 256, 0, stream>>>(ckbuf, sel);
  // sparse heavy path
  gemm1_kernel<<<dim3(TLEN / 128, KSEL / 128, BATCH), 256, 0, stream>>>(x, w_mfc, sel, h);
  gemm2_kernel<<<dim3(TLEN / 128, N_EMBD / 64, BATCH), 256, 0, stream>>>(h, wT, sel, out);
}

// Round 2
// 640.595 us; speedup vs baseline: 2.0163x; 2.0163x over previous
//
#include <hip/hip_runtime.h>

#define N_EMBD 768
#define FULL   12288
#define KSEL   3072
#define BATCH  8
#define TLEN   1024
#define HID    48

typedef short bf16x8 __attribute__((ext_vector_type(8)));
typedef float f32x4 __attribute__((ext_vector_type(4)));
typedef unsigned short u16x4 __attribute__((ext_vector_type(4)));
typedef unsigned short u16x8 __attribute__((ext_vector_type(8)));

#define MFMA(a, b, c) __builtin_amdgcn_mfma_f32_16x16x32_bf16((a), (b), (c), 0, 0, 0)
#define GLDS(g, l) __builtin_amdgcn_global_load_lds( \
    (const __attribute__((address_space(1))) void*)(const void*)(g), \
    (__attribute__((address_space(3))) void*)(void*)(l), 16, 0, 0)

__device__ __forceinline__ unsigned short f2bf(float f) {
  unsigned u = __float_as_uint(f);
  u += 0x7fffu + ((u >> 16) & 1u);   // round-to-nearest-even
  return (unsigned short)(u >> 16);
}
__device__ __forceinline__ float bf2f(unsigned short h) {
  return __uint_as_float(((unsigned)h) << 16);
}

// ---------------- pooled mean (deterministic 2-stage) ----------------
__global__ void pool_partial_kernel(const float* __restrict__ x, float* __restrict__ partial) {
  const int s = blockIdx.x;   // 0..15 (t-chunk of 64)
  const int b = blockIdx.y;   // 0..7
  const int tid = threadIdx.x;
  for (int d = tid; d < N_EMBD; d += 256) {
    float sum = 0.f;
    const float* base = x + ((size_t)b * TLEN + s * 64) * N_EMBD + d;
    #pragma unroll 4
    for (int t = 0; t < 64; ++t) sum += base[(size_t)t * N_EMBD];
    partial[(b * 16 + s) * N_EMBD + d] = sum;
  }
}

__global__ void pool_final_kernel(const float* __restrict__ partial, float* __restrict__ pooled) {
  const int b = blockIdx.x;
  const int tid = threadIdx.x;
  for (int d = tid; d < N_EMBD; d += 256) {
    float sum = 0.f;
    #pragma unroll
    for (int s = 0; s < 16; ++s) sum += partial[(b * 16 + s) * N_EMBD + d];
    pooled[b * N_EMBD + d] = sum * (1.f / TLEN);
  }
}

// ---------------- control net: ck = relu(pooled@w1^T)@w2^T ----------------
__global__ void control_kernel(const float* __restrict__ pooled, const float* __restrict__ w1,
                               const float* __restrict__ w2, float* __restrict__ ck) {
  const int b = blockIdx.x;
  const int tid = threadIdx.x;
  __shared__ float pool_s[N_EMBD];
  __shared__ float hid_s[HID];
  for (int d = tid; d < N_EMBD; d += 256) pool_s[d] = pooled[b * N_EMBD + d];
  __syncthreads();
  if (tid < HID) {
    float acc = 0.f;
    const float* wr = w1 + tid * N_EMBD;
    for (int d = 0; d < N_EMBD; ++d) acc = fmaf(pool_s[d], wr[d], acc);
    hid_s[tid] = fmaxf(acc, 0.f);
  }
  __syncthreads();
  for (int f = tid; f < FULL; f += 256) {
    const float* wr = w2 + (size_t)f * HID;
    float acc = 0.f;
    #pragma unroll
    for (int j = 0; j < HID; ++j) acc = fmaf(hid_s[j], wr[j], acc);
    ck[b * FULL + f] = acc;
  }
}

// ---------------- top-K selection (radix select, deterministic ties) ----------------
__global__ void topk_kernel(const float* __restrict__ ck, int* __restrict__ sel) {
  const int b = blockIdx.x;
  const int tid = threadIdx.x;
  __shared__ unsigned keys[FULL];        // 48 KB
  __shared__ unsigned red[256];
  __shared__ int sg[257], se[257];
  for (int f = tid; f < FULL; f += 256) {
    unsigned u = __float_as_uint(ck[b * FULL + f]);
    keys[f] = (u & 0x80000000u) ? ~u : (u | 0x80000000u);  // order-preserving map
  }
  __syncthreads();
  unsigned prefix = 0;
  int remaining = KSEL;
  const int f_lo = tid * (FULL / 256), f_hi = f_lo + (FULL / 256);
  for (int bit = 31; bit >= 0; --bit) {
    const unsigned want = prefix | (1u << bit);
    const unsigned shifted = want >> bit;
    unsigned cnt = 0;
    for (int f = f_lo; f < f_hi; ++f) cnt += ((keys[f] >> bit) == shifted) ? 1u : 0u;
    red[tid] = cnt;
    __syncthreads();
    for (int s = 128; s > 0; s >>= 1) {
      if (tid < s) red[tid] += red[tid + s];
      __syncthreads();
    }
    const int c = (int)red[0];
    __syncthreads();
    if (c >= remaining) prefix = want;
    else remaining -= c;
  }
  const unsigned kth = prefix;
  int cg = 0, ce = 0;
  for (int f = f_lo; f < f_hi; ++f) { cg += (keys[f] > kth) ? 1 : 0; ce += (keys[f] == kth) ? 1 : 0; }
  sg[tid] = cg; se[tid] = ce;
  __syncthreads();
  if (tid == 0) {
    int ag = 0, ae = 0;
    for (int i = 0; i < 256; ++i) {
      int tg = sg[i], te = se[i];
      sg[i] = ag; se[i] = ae;
      ag += tg; ae += te;
    }
    sg[256] = ag;
  }
  __syncthreads();
  const int ng = sg[256];
  int gpos = sg[tid], epos = se[tid];
  for (int f = f_lo; f < f_hi; ++f) {
    const unsigned k = keys[f];
    if (k > kth) {
      sel[b * KSEL + (gpos++)] = f;
    } else if (k == kth) {
      const int p = ng + epos;
      if (p < KSEL) sel[b * KSEL + p] = f;
      ++epos;
    }
  }
}

// ---------------- transpose w_proj (768 x 12288) -> wT (12288 x 768) fp32 ----------------
__global__ void transpose_kernel(const float* __restrict__ wproj, float* __restrict__ wT) {
  __shared__ float tile[32][33];
  const int f0 = blockIdx.x * 32;
  const int e0 = blockIdx.y * 32;
  const int tx = threadIdx.x, ty = threadIdx.y;  // (32, 8)
  #pragma unroll
  for (int q = 0; q < 4; ++q)
    tile[ty + q * 8][tx] = wproj[(size_t)(e0 + ty + q * 8) * FULL + f0 + tx];
  __syncthreads();
  #pragma unroll
  for (int q = 0; q < 4; ++q)
    wT[(size_t)(f0 + ty + q * 8) * N_EMBD + e0 + tx] = tile[tx][ty + q * 8];
}

// ---------------- fp32 -> (bf16 hi, bf16 lo) elementwise split ----------------
__global__ void split_kernel(const float* __restrict__ src, unsigned short* __restrict__ hi,
                             unsigned short* __restrict__ lo, int n4) {
  const int idx = blockIdx.x * 256 + threadIdx.x;
  if (idx >= n4) return;
  const float4 v = ((const float4*)src)[idx];
  u16x4 h, l;
  h.x = f2bf(v.x); l.x = f2bf(v.x - bf2f(h.x));
  h.y = f2bf(v.y); l.y = f2bf(v.y - bf2f(h.y));
  h.z = f2bf(v.z); l.z = f2bf(v.z - bf2f(h.z));
  h.w = f2bf(v.w); l.w = f2bf(v.w - bf2f(h.w));
  ((u16x4*)hi)[idx] = h;
  ((u16x4*)lo)[idx] = l;
}

// ---------------- gather+transpose w_proj^T rows -> wp[b][e][kk] bf16 hi/lo ----------------
// wp[b][e][kk] = w_proj[e][sel[b][kk]]  (K-major operand for GEMM2)
__global__ void gather_wp_kernel(const float* __restrict__ wT, const int* __restrict__ sel,
                                 unsigned short* __restrict__ wph, unsigned short* __restrict__ wpl) {
  __shared__ float tile[32][65];
  const int kk0 = blockIdx.x * 32;
  const int e0  = blockIdx.y * 64;
  const int b   = blockIdx.z;
  const int tid = threadIdx.x;
  const int* selb = sel + b * KSEL;
  {
    const int r = tid >> 3;          // 0..31 (kk row)
    const int c8 = tid & 7;          // 8 floats each
    const int f = selb[kk0 + r];
    const float4* p = (const float4*)(wT + (size_t)f * N_EMBD + e0 + c8 * 8);
    float4 v0 = p[0], v1 = p[1];
    tile[r][c8 * 8 + 0] = v0.x; tile[r][c8 * 8 + 1] = v0.y;
    tile[r][c8 * 8 + 2] = v0.z; tile[r][c8 * 8 + 3] = v0.w;
    tile[r][c8 * 8 + 4] = v1.x; tile[r][c8 * 8 + 5] = v1.y;
    tile[r][c8 * 8 + 6] = v1.z; tile[r][c8 * 8 + 7] = v1.w;
  }
  __syncthreads();
  const int e = tid >> 2;            // 0..63
  const int kg = tid & 3;            // 8 kk each
  u16x8 oh, ol;
  #pragma unroll
  for (int j = 0; j < 8; ++j) {
    const float v = tile[kg * 8 + j][e];
    const unsigned short h = f2bf(v);
    oh[j] = h;
    ol[j] = f2bf(v - bf2f(h));
  }
  const size_t off = ((size_t)(b * N_EMBD + e0 + e)) * KSEL + kk0 + kg * 8;
  *(u16x8*)(wph + off) = oh;
  *(u16x8*)(wpl + off) = ol;
}

// ---------------- GEMM1 (MFMA split-bf16): h = relu(x @ gather(w_mfc, sel)^T) ----------------
// 128x128 tile, BK=32, 4 waves (2x2 of 64x64), 16x16x32 bf16 MFMA, 3-product hi/lo.
__global__ __launch_bounds__(256) void gemm1_mfma(
    const unsigned short* __restrict__ xh, const unsigned short* __restrict__ xl,
    const unsigned short* __restrict__ wh, const unsigned short* __restrict__ wl,
    const int* __restrict__ sel,
    unsigned short* __restrict__ hh, unsigned short* __restrict__ hl) {
  __shared__ __align__(16) char sm[32768];  // Ahi|Alo|Bhi|Blo, 8KB each, rows of 64B (32 bf16)
  const int nx = TLEN / 128, ny = KSEL / 128;          // 8, 24
  const int nwg = nx * ny * BATCH;                     // 1536 (divisible by 8)
  int lin = blockIdx.x + nx * (blockIdx.y + ny * blockIdx.z);
  int swz = (lin & 7) * (nwg >> 3) + (lin >> 3);       // XCD-contiguous chunks
  const int bx = swz % nx; int tmp = swz / nx;
  const int by = tmp % ny; const int b = tmp / ny;
  const int t0 = bx * 128, f0 = by * 128;

  const int tid = threadIdx.x;
  const int wv = tid >> 6, lane = tid & 63;
  const int srow = tid >> 2, sslot = tid & 3;
  const int wb = wv * 1024;

  const char* pxh = (const char*)xh;
  const char* pxl = (const char*)xl;
  const char* pwh = (const char*)wh;
  const char* pwl = (const char*)wl;
  const size_t aoff  = ((size_t)(b * TLEN + t0 + srow)) * 1536 + sslot * 16;  // row stride 768*2B
  const size_t aoff2 = aoff + (size_t)64 * 1536;
  const int* selb = sel + b * KSEL;
  const size_t boff  = (size_t)selb[f0 + srow] * 1536 + sslot * 16;
  const size_t boff2 = (size_t)selb[f0 + srow + 64] * 1536 + sslot * 16;

  const int fr = lane & 15, kg = lane >> 4;
  const int fo = fr * 64 + kg * 16;
  const int m0 = (wv >> 1) * 64, n0 = (wv & 1) * 64;

  f32x4 acc[4][4];
  const f32x4 z4 = {0.f, 0.f, 0.f, 0.f};
  #pragma unroll
  for (int mi = 0; mi < 4; ++mi)
    #pragma unroll
    for (int ni = 0; ni < 4; ++ni) acc[mi][ni] = z4;

  for (int d = 0; d < N_EMBD * 2; d += 64) {
    GLDS(pxh + aoff  + d, sm + 0     + wb);
    GLDS(pxh + aoff2 + d, sm + 4096  + wb);
    GLDS(pxl + aoff  + d, sm + 8192  + wb);
    GLDS(pxl + aoff2 + d, sm + 12288 + wb);
    GLDS(pwh + boff  + d, sm + 16384 + wb);
    GLDS(pwh + boff2 + d, sm + 20480 + wb);
    GLDS(pwl + boff  + d, sm + 24576 + wb);
    GLDS(pwl + boff2 + d, sm + 28672 + wb);
    __syncthreads();
    bf16x8 ah[4], al[4], bh[4], bl[4];
    #pragma unroll
    for (int i = 0; i < 4; ++i) {
      const int ra = (m0 + i * 16) * 64 + fo;
      const int rb = (n0 + i * 16) * 64 + fo;
      ah[i] = *(const bf16x8*)(sm + 0     + ra);
      al[i] = *(const bf16x8*)(sm + 8192  + ra);
      bh[i] = *(const bf16x8*)(sm + 16384 + rb);
      bl[i] = *(const bf16x8*)(sm + 24576 + rb);
    }
    #pragma unroll
    for (int mi = 0; mi < 4; ++mi)
      #pragma unroll
      for (int ni = 0; ni < 4; ++ni) {
        acc[mi][ni] = MFMA(ah[mi], bh[ni], acc[mi][ni]);
        acc[mi][ni] = MFMA(al[mi], bh[ni], acc[mi][ni]);
        acc[mi][ni] = MFMA(ah[mi], bl[ni], acc[mi][ni]);
      }
    __syncthreads();
  }
  // epilogue: relu + split -> bf16 hi/lo   (C/D: col=lane&15, row=(lane>>4)*4+j)
  const int rowg = lane >> 4, colc = lane & 15;
  #pragma unroll
  for (int mi = 0; mi < 4; ++mi)
    #pragma unroll
    for (int ni = 0; ni < 4; ++ni) {
      const int m = t0 + m0 + mi * 16 + rowg * 4;
      const int n = f0 + n0 + ni * 16 + colc;
      const size_t base = ((size_t)(b * TLEN + m)) * KSEL + n;
      #pragma unroll
      for (int j = 0; j < 4; ++j) {
        const float v = fmaxf(acc[mi][ni][j], 0.f);
        const unsigned short h = f2bf(v);
        hh[base + (size_t)j * KSEL] = h;
        hl[base + (size_t)j * KSEL] = f2bf(v - bf2f(h));
      }
    }
}

// ---------------- GEMM2 (MFMA split-bf16): out = h @ wp^T ----------------
// 128x64 tile, BK=32, 4 waves (2x2 of 64x32).
__global__ __launch_bounds__(256) void gemm2_mfma(
    const unsigned short* __restrict__ hh, const unsigned short* __restrict__ hl,
    const unsigned short* __restrict__ wph, const unsigned short* __restrict__ wpl,
    float* __restrict__ out) {
  __shared__ __align__(16) char sm[24576];  // Ahi(8K)|Alo(8K)|Bhi(4K)|Blo(4K)
  const int nx = TLEN / 128, ny = N_EMBD / 64;         // 8, 12
  const int nwg = nx * ny * BATCH;                     // 768
  int lin = blockIdx.x + nx * (blockIdx.y + ny * blockIdx.z);
  int swz = (lin & 7) * (nwg >> 3) + (lin >> 3);
  const int bx = swz % nx; int tmp = swz / nx;
  const int by = tmp % ny; const int b = tmp / ny;
  const int t0 = bx * 128, e0 = by * 64;

  const int tid = threadIdx.x;
  const int wv = tid >> 6, lane = tid & 63;
  const int srow = tid >> 2, sslot = tid & 3;
  const int wb = wv * 1024;

  const char* phh = (const char*)hh;
  const char* phl = (const char*)hl;
  const char* pwh = (const char*)wph;
  const char* pwl = (const char*)wpl;
  const size_t aoff  = ((size_t)(b * TLEN + t0 + srow)) * 6144 + sslot * 16;  // row stride 3072*2B
  const size_t aoff2 = aoff + (size_t)64 * 6144;
  const size_t boff  = ((size_t)(b * N_EMBD + e0 + srow)) * 6144 + sslot * 16;

  const int fr = lane & 15, kg = lane >> 4;
  const int fo = fr * 64 + kg * 16;
  const int m0 = (wv >> 1) * 64, n0 = (wv & 1) * 32;

  f32x4 acc[4][2];
  const f32x4 z4 = {0.f, 0.f, 0.f, 0.f};
  #pragma unroll
  for (int mi = 0; mi < 4; ++mi)
    #pragma unroll
    for (int ni = 0; ni < 2; ++ni) acc[mi][ni] = z4;

  for (int d = 0; d < KSEL * 2; d += 64) {
    GLDS(phh + aoff  + d, sm + 0     + wb);
    GLDS(phh + aoff2 + d, sm + 4096  + wb);
    GLDS(phl + aoff  + d, sm + 8192  + wb);
    GLDS(phl + aoff2 + d, sm + 12288 + wb);
    GLDS(pwh + boff  + d, sm + 16384 + wb);
    GLDS(pwl + boff  + d, sm + 20480 + wb);
    __syncthreads();
    bf16x8 ah[4], al[4], bh[2], bl[2];
    #pragma unroll
    for (int i = 0; i < 4; ++i) {
      const int ra = (m0 + i * 16) * 64 + fo;
      ah[i] = *(const bf16x8*)(sm + 0    + ra);
      al[i] = *(const bf16x8*)(sm + 8192 + ra);
    }
    #pragma unroll
    for (int i = 0; i < 2; ++i) {
      const int rb = (n0 + i * 16) * 64 + fo;
      bh[i] = *(const bf16x8*)(sm + 16384 + rb);
      bl[i] = *(const bf16x8*)(sm + 20480 + rb);
    }
    #pragma unroll
    for (int mi = 0; mi < 4; ++mi)
      #pragma unroll
      for (int ni = 0; ni < 2; ++ni) {
        acc[mi][ni] = MFMA(ah[mi], bh[ni], acc[mi][ni]);
        acc[mi][ni] = MFMA(al[mi], bh[ni], acc[mi][ni]);
        acc[mi][ni] = MFMA(ah[mi], bl[ni], acc[mi][ni]);
      }
    __syncthreads();
  }
  const int rowg = lane >> 4, colc = lane & 15;
  #pragma unroll
  for (int mi = 0; mi < 4; ++mi)
    #pragma unroll
    for (int ni = 0; ni < 2; ++ni) {
      const int m = t0 + m0 + mi * 16 + rowg * 4;
      const int e = e0 + n0 + ni * 16 + colc;
      const size_t base = ((size_t)(b * TLEN + m)) * N_EMBD + e;
      #pragma unroll
      for (int j = 0; j < 4; ++j)
        out[base + (size_t)j * N_EMBD] = acc[mi][ni][j];
    }
}

// ---------------- launch ----------------
extern "C" void kernel_launch(void* const* d_in, const int* in_sizes, int n_in,
                              void* d_out, int out_size, void* d_ws, size_t ws_size,
                              hipStream_t stream) {
  const float* x      = (const float*)d_in[0];
  const float* w1     = (const float*)d_in[1];
  const float* w2     = (const float*)d_in[2];
  const float* w_mfc  = (const float*)d_in[3];
  const float* w_proj = (const float*)d_in[4];
  float* out = (float*)d_out;

  char* ws = (char*)d_ws;
  size_t off = 0;
  auto alloc = [&](size_t bytes) -> void* {
    void* p = ws + off;
    off += (bytes + 255) & ~(size_t)255;
    return p;
  };
  const size_t NX = (size_t)BATCH * TLEN * N_EMBD;   // 6,291,456
  const size_t NW = (size_t)FULL * N_EMBD;           // 9,437,184
  const size_t NWP = (size_t)BATCH * N_EMBD * KSEL;  // 18,874,368
  const size_t NH = (size_t)BATCH * TLEN * KSEL;     // 25,165,824

  float* partial = (float*)alloc((size_t)BATCH * 16 * N_EMBD * 4);
  float* pooled  = (float*)alloc((size_t)BATCH * N_EMBD * 4);
  float* ckbuf   = (float*)alloc((size_t)BATCH * FULL * 4);
  int*   sel     = (int*)  alloc((size_t)BATCH * KSEL * 4);
  unsigned short* xh  = (unsigned short*)alloc(NX * 2);
  unsigned short* xl  = (unsigned short*)alloc(NX * 2);
  unsigned short* wh  = (unsigned short*)alloc(NW * 2);
  unsigned short* wl  = (unsigned short*)alloc(NW * 2);
  unsigned short* wph = (unsigned short*)alloc(NWP * 2);
  unsigned short* wpl = (unsigned short*)alloc(NWP * 2);
  unsigned short* hh  = (unsigned short*)alloc(NH * 2);
  unsigned short* hl  = (unsigned short*)alloc(NH * 2);
  float* wT = (float*)hh;  // alias: wT (37.7MB fp32) lives in hh (50.3MB); dead before gemm1 writes hh

  // fp32 transpose of w_proj (source for the per-batch gather)
  transpose_kernel<<<dim3(FULL / 32, N_EMBD / 32), dim3(32, 8), 0, stream>>>(w_proj, wT);
  // bf16 hi/lo splits
  split_kernel<<<(int)(NX / 4 / 256), 256, 0, stream>>>(x, xh, xl, (int)(NX / 4));
  split_kernel<<<(int)(NW / 4 / 256), 256, 0, stream>>>(w_mfc, wh, wl, (int)(NW / 4));
  // control path (exact fp32, deterministic)
  pool_partial_kernel<<<dim3(16, BATCH), 256, 0, stream>>>(x, partial);
  pool_final_kernel<<<BATCH, 256, 0, stream>>>(partial, pooled);
  control_kernel<<<BATCH, 256, 0, stream>>>(pooled, w1, w2, ckbuf);
  topk_kernel<<<BATCH, 256, 0, stream>>>(ckbuf, sel);
  // per-batch compacted w_proj operand (reads wT, then wT is dead)
  gather_wp_kernel<<<dim3(KSEL / 32, N_EMBD / 64, BATCH), 256, 0, stream>>>(wT, sel, wph, wpl);
  // sparse heavy path on MFMA
  gemm1_mfma<<<dim3(TLEN / 128, KSEL / 128, BATCH), 256, 0, stream>>>(xh, xl, wh, wl, sel, hh, hl);
  gemm2_mfma<<<dim3(TLEN / 128, N_EMBD / 64, BATCH), 256, 0, stream>>>(hh, hl, wph, wpl, out);
}

// Round 3
// 618.774 us; speedup vs baseline: 2.0874x; 1.0353x over previous
//
#include <hip/hip_runtime.h>

#define N_EMBD 768
#define FULL   12288
#define KSEL   3072
#define BATCH  8
#define TLEN   1024
#define HID    48

typedef short bf16x8 __attribute__((ext_vector_type(8)));
typedef float f32x4 __attribute__((ext_vector_type(4)));
typedef unsigned short u16x4 __attribute__((ext_vector_type(4)));
typedef unsigned short u16x8 __attribute__((ext_vector_type(8)));

#define MFMA(a, b, c) __builtin_amdgcn_mfma_f32_16x16x32_bf16((a), (b), (c), 0, 0, 0)
#define GLDS(g, l) __builtin_amdgcn_global_load_lds( \
    (const __attribute__((address_space(1))) void*)(const void*)(g), \
    (__attribute__((address_space(3))) void*)(void*)(l), 16, 0, 0)

__device__ __forceinline__ unsigned short f2bf(float f) {
  unsigned u = __float_as_uint(f);
  u += 0x7fffu + ((u >> 16) & 1u);   // round-to-nearest-even
  return (unsigned short)(u >> 16);
}
__device__ __forceinline__ float bf2f(unsigned short h) {
  return __uint_as_float(((unsigned)h) << 16);
}

// ---------------- fused: split x -> bf16 hi/lo + partial pooling ----------------
// 192 threads: each owns 4 d's; sums 64 sequential t's (identical order to the
// previous 2-stage pooling -> bit-identical pooled values -> identical top-k).
__global__ void split_pool_x(const float* __restrict__ x, unsigned short* __restrict__ xh,
                             unsigned short* __restrict__ xl, float* __restrict__ partial) {
  const int s = blockIdx.x;   // 0..15 t-chunk of 64
  const int b = blockIdx.y;
  const int d = threadIdx.x * 4;
  const float* base = x + ((size_t)(b * TLEN + s * 64)) * N_EMBD + d;
  float4 sum = {0.f, 0.f, 0.f, 0.f};
  for (int t = 0; t < 64; ++t) {
    const float4 v = *(const float4*)(base + (size_t)t * N_EMBD);
    sum.x += v.x; sum.y += v.y; sum.z += v.z; sum.w += v.w;
    u16x4 h, l;
    h.x = f2bf(v.x); l.x = f2bf(v.x - bf2f(h.x));
    h.y = f2bf(v.y); l.y = f2bf(v.y - bf2f(h.y));
    h.z = f2bf(v.z); l.z = f2bf(v.z - bf2f(h.z));
    h.w = f2bf(v.w); l.w = f2bf(v.w - bf2f(h.w));
    const size_t o = ((size_t)(b * TLEN + s * 64 + t)) * N_EMBD + d;
    *(u16x4*)(xh + o) = h;
    *(u16x4*)(xl + o) = l;
  }
  float* pp = partial + (b * 16 + s) * N_EMBD + d;
  pp[0] = sum.x; pp[1] = sum.y; pp[2] = sum.z; pp[3] = sum.w;
}

__global__ void pool_final_kernel(const float* __restrict__ partial, float* __restrict__ pooled) {
  const int b = blockIdx.x;
  const int tid = threadIdx.x;
  for (int d = tid; d < N_EMBD; d += 256) {
    float sum = 0.f;
    #pragma unroll
    for (int s = 0; s < 16; ++s) sum += partial[(b * 16 + s) * N_EMBD + d];
    pooled[b * N_EMBD + d] = sum * (1.f / TLEN);
  }
}

// ---------------- control net: ck = relu(pooled@w1^T)@w2^T ----------------
__global__ void control_kernel(const float* __restrict__ pooled, const float* __restrict__ w1,
                               const float* __restrict__ w2, float* __restrict__ ck) {
  const int b = blockIdx.x;
  const int tid = threadIdx.x;
  __shared__ float pool_s[N_EMBD];
  __shared__ float hid_s[HID];
  for (int d = tid; d < N_EMBD; d += 256) pool_s[d] = pooled[b * N_EMBD + d];
  __syncthreads();
  if (tid < HID) {
    float acc = 0.f;
    const float* wr = w1 + tid * N_EMBD;
    for (int d = 0; d < N_EMBD; ++d) acc = fmaf(pool_s[d], wr[d], acc);
    hid_s[tid] = fmaxf(acc, 0.f);
  }
  __syncthreads();
  for (int f = tid; f < FULL; f += 256) {
    const float* wr = w2 + (size_t)f * HID;
    float acc = 0.f;
    #pragma unroll
    for (int j = 0; j < HID; ++j) acc = fmaf(hid_s[j], wr[j], acc);
    ck[b * FULL + f] = acc;
  }
}

// ---------------- top-K selection (radix select, keys in registers) ----------------
// Ties broken by lowest index (matches jax.lax.top_k). Wave shuffle-reduce: 2 barriers/bit.
__global__ void topk_kernel(const float* __restrict__ ck, int* __restrict__ sel) {
  const int b = blockIdx.x;
  const int tid = threadIdx.x;               // 256
  const int lane = tid & 63, wv = tid >> 6;
  unsigned key[48];
  const int f_lo = tid * 48;
  #pragma unroll
  for (int i = 0; i < 48; ++i) {
    unsigned u = __float_as_uint(ck[b * FULL + f_lo + i]);
    key[i] = (u & 0x80000000u) ? ~u : (u | 0x80000000u);  // order-preserving map
  }
  __shared__ unsigned redw[4];
  __shared__ int sg[257], se[257];
  unsigned prefix = 0;
  int remaining = KSEL;
  for (int bit = 31; bit >= 0; --bit) {
    const unsigned want = prefix | (1u << bit);
    const unsigned shifted = want >> bit;
    int cnt = 0;
    #pragma unroll
    for (int i = 0; i < 48; ++i) cnt += ((key[i] >> bit) == shifted) ? 1 : 0;
    #pragma unroll
    for (int off = 1; off < 64; off <<= 1) cnt += __shfl_xor(cnt, off, 64);
    if (lane == 0) redw[wv] = (unsigned)cnt;
    __syncthreads();
    const int c = (int)(redw[0] + redw[1] + redw[2] + redw[3]);
    __syncthreads();
    if (c >= remaining) prefix = want;
    else remaining -= c;
  }
  const unsigned kth = prefix;  // value of the K-th largest key
  int cg = 0, ce = 0;
  #pragma unroll
  for (int i = 0; i < 48; ++i) { cg += (key[i] > kth) ? 1 : 0; ce += (key[i] == kth) ? 1 : 0; }
  sg[tid] = cg; se[tid] = ce;
  __syncthreads();
  if (tid == 0) {
    int ag = 0, ae = 0;
    for (int i = 0; i < 256; ++i) {
      int tg = sg[i], te = se[i];
      sg[i] = ag; se[i] = ae;
      ag += tg; ae += te;
    }
    sg[256] = ag;
  }
  __syncthreads();
  const int ng = sg[256];
  int gpos = sg[tid], epos = se[tid];
  #pragma unroll
  for (int i = 0; i < 48; ++i) {
    const unsigned k = key[i];
    const int f = f_lo + i;
    if (k > kth) {
      sel[b * KSEL + (gpos++)] = f;
    } else if (k == kth) {
      const int p = ng + epos;
      if (p < KSEL) sel[b * KSEL + p] = f;
      ++epos;
    }
  }
}

// ---------------- fp32 -> (bf16 hi, bf16 lo) elementwise split (w_mfc) ----------------
__global__ void split_kernel(const float* __restrict__ src, unsigned short* __restrict__ hi,
                             unsigned short* __restrict__ lo, int n4) {
  const int idx = blockIdx.x * 256 + threadIdx.x;
  if (idx >= n4) return;
  const float4 v = ((const float4*)src)[idx];
  u16x4 h, l;
  h.x = f2bf(v.x); l.x = f2bf(v.x - bf2f(h.x));
  h.y = f2bf(v.y); l.y = f2bf(v.y - bf2f(h.y));
  h.z = f2bf(v.z); l.z = f2bf(v.z - bf2f(h.z));
  h.w = f2bf(v.w); l.w = f2bf(v.w - bf2f(h.w));
  ((u16x4*)hi)[idx] = h;
  ((u16x4*)lo)[idx] = l;
}

// ---------------- gather w_proj along contiguous axis -> wp[b][e][kk] bf16 hi/lo ----------------
// wp[b][e][kk] = w_proj[e][sel[b][kk]]  -- no transpose needed (gather on the f axis).
__global__ void gather_wp_kernel(const float* __restrict__ wproj, const int* __restrict__ sel,
                                 unsigned short* __restrict__ wph, unsigned short* __restrict__ wpl) {
  const int kk = blockIdx.x * 256 + threadIdx.x;   // 0..3071
  const int e  = blockIdx.y;                       // 0..767
  const int b  = blockIdx.z;
  const int f = sel[b * KSEL + kk];
  const float v = wproj[(size_t)e * FULL + f];
  const unsigned short h = f2bf(v);
  const size_t off = ((size_t)(b * N_EMBD + e)) * KSEL + kk;
  wph[off] = h;
  wpl[off] = f2bf(v - bf2f(h));
}

// ---------------- GEMM1 (MFMA split-bf16, 3-product): h = relu(x @ gather(w_mfc, sel)^T) ----
// 128x128 tile, BK=32, 4 waves (2x2 of 64x64). Output: bf16 hh only, coalesced via LDS repack.
__global__ __launch_bounds__(256) void gemm1_mfma(
    const unsigned short* __restrict__ xh, const unsigned short* __restrict__ xl,
    const unsigned short* __restrict__ wh, const unsigned short* __restrict__ wl,
    const int* __restrict__ sel, unsigned short* __restrict__ hh) {
  __shared__ __align__(16) char sm[32768];  // Ahi|Alo|Bhi|Blo, 8KB each, rows of 64B (32 bf16)
  const int nx = TLEN / 128, ny = KSEL / 128;          // 8, 24
  const int nwg = nx * ny * BATCH;                     // 1536 (divisible by 8)
  int lin = blockIdx.x + nx * (blockIdx.y + ny * blockIdx.z);
  int swz = (lin & 7) * (nwg >> 3) + (lin >> 3);       // XCD-contiguous chunks
  const int bx = swz % nx; int tmp = swz / nx;
  const int by = tmp % ny; const int b = tmp / ny;
  const int t0 = bx * 128, f0 = by * 128;

  const int tid = threadIdx.x;
  const int wv = tid >> 6, lane = tid & 63;
  const int srow = tid >> 2, sslot = tid & 3;
  const int wb = wv * 1024;

  const char* pxh = (const char*)xh;
  const char* pxl = (const char*)xl;
  const char* pwh = (const char*)wh;
  const char* pwl = (const char*)wl;
  const size_t aoff  = ((size_t)(b * TLEN + t0 + srow)) * 1536 + sslot * 16;  // row stride 768*2B
  const size_t aoff2 = aoff + (size_t)64 * 1536;
  const int* selb = sel + b * KSEL;
  const size_t boff  = (size_t)selb[f0 + srow] * 1536 + sslot * 16;
  const size_t boff2 = (size_t)selb[f0 + srow + 64] * 1536 + sslot * 16;

  const int fr = lane & 15, kg = lane >> 4;
  const int fo = fr * 64 + kg * 16;
  const int m0 = (wv >> 1) * 64, n0 = (wv & 1) * 64;

  f32x4 acc[4][4];
  const f32x4 z4 = {0.f, 0.f, 0.f, 0.f};
  #pragma unroll
  for (int mi = 0; mi < 4; ++mi)
    #pragma unroll
    for (int ni = 0; ni < 4; ++ni) acc[mi][ni] = z4;

  for (int d = 0; d < N_EMBD * 2; d += 64) {
    GLDS(pxh + aoff  + d, sm + 0     + wb);
    GLDS(pxh + aoff2 + d, sm + 4096  + wb);
    GLDS(pxl + aoff  + d, sm + 8192  + wb);
    GLDS(pxl + aoff2 + d, sm + 12288 + wb);
    GLDS(pwh + boff  + d, sm + 16384 + wb);
    GLDS(pwh + boff2 + d, sm + 20480 + wb);
    GLDS(pwl + boff  + d, sm + 24576 + wb);
    GLDS(pwl + boff2 + d, sm + 28672 + wb);
    __syncthreads();
    bf16x8 ah[4], al[4], bh[4], bl[4];
    #pragma unroll
    for (int i = 0; i < 4; ++i) {
      const int ra = (m0 + i * 16) * 64 + fo;
      const int rb = (n0 + i * 16) * 64 + fo;
      ah[i] = *(const bf16x8*)(sm + 0     + ra);
      al[i] = *(const bf16x8*)(sm + 8192  + ra);
      bh[i] = *(const bf16x8*)(sm + 16384 + rb);
      bl[i] = *(const bf16x8*)(sm + 24576 + rb);
    }
    #pragma unroll
    for (int mi = 0; mi < 4; ++mi)
      #pragma unroll
      for (int ni = 0; ni < 4; ++ni) {
        acc[mi][ni] = MFMA(ah[mi], bh[ni], acc[mi][ni]);
        acc[mi][ni] = MFMA(al[mi], bh[ni], acc[mi][ni]);
        acc[mi][ni] = MFMA(ah[mi], bl[ni], acc[mi][ni]);
      }
    __syncthreads();
  }
  // epilogue: relu -> bf16, repack through LDS, coalesced 16B stores.
  // C/D layout: col=lane&15, row=(lane>>4)*4+j  (m89-verified)
  unsigned short* lh = (unsigned short*)sm;  // [128][128] bf16 = 32KB
  const int rowg = lane >> 4, colc = lane & 15;
  #pragma unroll
  for (int mi = 0; mi < 4; ++mi)
    #pragma unroll
    for (int ni = 0; ni < 4; ++ni) {
      const int row = m0 + mi * 16 + rowg * 4;
      const int col = n0 + ni * 16 + colc;
      #pragma unroll
      for (int j = 0; j < 4; ++j)
        lh[(row + j) * 128 + col] = f2bf(fmaxf(acc[mi][ni][j], 0.f));
    }
  __syncthreads();
  const int orow = tid >> 4, oc = tid & 15;
  #pragma unroll
  for (int i2 = 0; i2 < 8; ++i2) {
    const int row = orow + i2 * 16;
    const u16x8 v = *(const u16x8*)&lh[row * 128 + oc * 8];
    *(u16x8*)(hh + ((size_t)(b * TLEN + t0 + row)) * KSEL + f0 + oc * 8) = v;
  }
}

// ---------------- GEMM2 (MFMA 2-product, double-buffered): out = hh @ (wph+wpl)^T ----------------
// 128x64 tile, BK=32, 4 waves (2x2 of 64x32). Stage(next) overlaps compute(cur); 1 barrier/step.
__global__ __launch_bounds__(256) void gemm2_mfma(
    const unsigned short* __restrict__ hh,
    const unsigned short* __restrict__ wph, const unsigned short* __restrict__ wpl,
    float* __restrict__ out) {
  __shared__ __align__(16) char sm[32768];  // 2 bufs x (A 8K | Bh 4K | Bl 4K)
  const int nx = TLEN / 128, ny = N_EMBD / 64;         // 8, 12
  const int nwg = nx * ny * BATCH;                     // 768
  int lin = blockIdx.x + nx * (blockIdx.y + ny * blockIdx.z);
  int swz = (lin & 7) * (nwg >> 3) + (lin >> 3);
  const int bx = swz % nx; int tmp = swz / nx;
  const int by = tmp % ny; const int b = tmp / ny;
  const int t0 = bx * 128, e0 = by * 64;

  const int tid = threadIdx.x;
  const int wv = tid >> 6, lane = tid & 63;
  const int wb = wv * 1024;

  const char* pa  = (const char*)hh;
  const char* pbh = (const char*)wph;
  const char* pbl = (const char*)wpl;
  const size_t aoff  = ((size_t)(b * TLEN + t0 + (tid >> 2))) * 6144 + (tid & 3) * 16;
  const size_t aoff2 = aoff + (size_t)64 * 6144;
  const size_t boff  = ((size_t)(b * N_EMBD + e0 + (tid >> 2))) * 6144 + (tid & 3) * 16;

  const int fr = lane & 15, kg = lane >> 4;
  const int fo = fr * 64 + kg * 16;
  const int m0 = (wv >> 1) * 64, n0 = (wv & 1) * 32;

  f32x4 acc[4][2];
  const f32x4 z4 = {0.f, 0.f, 0.f, 0.f};
  #pragma unroll
  for (int mi = 0; mi < 4; ++mi)
    #pragma unroll
    for (int ni = 0; ni < 2; ++ni) acc[mi][ni] = z4;

  auto stage = [&](int bo, int d) {
    GLDS(pa  + aoff  + d, sm + bo + 0     + wb);
    GLDS(pa  + aoff2 + d, sm + bo + 4096  + wb);
    GLDS(pbh + boff  + d, sm + bo + 8192  + wb);
    GLDS(pbl + boff  + d, sm + bo + 12288 + wb);
  };
  stage(0, 0);
  __syncthreads();                       // drains vmcnt(0): buf0 ready
  const int NIT = KSEL * 2 / 64;         // 96
  for (int it = 0; it < NIT; ++it) {
    const int cur = (it & 1) << 14;
    if (it + 1 < NIT) stage(cur ^ 16384, (it + 1) * 64);  // overlaps with compute below
    bf16x8 ah[4], bh[2], bl[2];
    #pragma unroll
    for (int i = 0; i < 4; ++i)
      ah[i] = *(const bf16x8*)(sm + cur + (m0 + i * 16) * 64 + fo);
    #pragma unroll
    for (int i = 0; i < 2; ++i) {
      bh[i] = *(const bf16x8*)(sm + cur + 8192  + (n0 + i * 16) * 64 + fo);
      bl[i] = *(const bf16x8*)(sm + cur + 12288 + (n0 + i * 16) * 64 + fo);
    }
    #pragma unroll
    for (int mi = 0; mi < 4; ++mi)
      #pragma unroll
      for (int ni = 0; ni < 2; ++ni) {
        acc[mi][ni] = MFMA(ah[mi], bh[ni], acc[mi][ni]);
        acc[mi][ni] = MFMA(ah[mi], bl[ni], acc[mi][ni]);
      }
    __syncthreads();                     // drains next-buf loads; guards buf reuse
  }
  const int rowg = lane >> 4, colc = lane & 15;
  #pragma unroll
  for (int mi = 0; mi < 4; ++mi)
    #pragma unroll
    for (int ni = 0; ni < 2; ++ni) {
      const int m = t0 + m0 + mi * 16 + rowg * 4;
      const int e = e0 + n0 + ni * 16 + colc;
      const size_t base = ((size_t)(b * TLEN + m)) * N_EMBD + e;
      #pragma unroll
      for (int j = 0; j < 4; ++j)
        out[base + (size_t)j * N_EMBD] = acc[mi][ni][j];
    }
}

// ---------------- launch ----------------
extern "C" void kernel_launch(void* const* d_in, const int* in_sizes, int n_in,
                              void* d_out, int out_size, void* d_ws, size_t ws_size,
                              hipStream_t stream) {
  const float* x      = (const float*)d_in[0];
  const float* w1     = (const float*)d_in[1];
  const float* w2     = (const float*)d_in[2];
  const float* w_mfc  = (const float*)d_in[3];
  const float* w_proj = (const float*)d_in[4];
  float* out = (float*)d_out;

  char* ws = (char*)d_ws;
  size_t off = 0;
  auto alloc = [&](size_t bytes) -> void* {
    void* p = ws + off;
    off += (bytes + 255) & ~(size_t)255;
    return p;
  };
  const size_t NX  = (size_t)BATCH * TLEN * N_EMBD;   // 6,291,456
  const size_t NW  = (size_t)FULL * N_EMBD;           // 9,437,184
  const size_t NWP = (size_t)BATCH * N_EMBD * KSEL;   // 18,874,368
  const size_t NH  = (size_t)BATCH * TLEN * KSEL;     // 25,165,824

  float* partial = (float*)alloc((size_t)BATCH * 16 * N_EMBD * 4);
  float* pooled  = (float*)alloc((size_t)BATCH * N_EMBD * 4);
  float* ckbuf   = (float*)alloc((size_t)BATCH * FULL * 4);
  int*   sel     = (int*)  alloc((size_t)BATCH * KSEL * 4);
  unsigned short* xh  = (unsigned short*)alloc(NX * 2);
  unsigned short* xl  = (unsigned short*)alloc(NX * 2);
  unsigned short* wh  = (unsigned short*)alloc(NW * 2);
  unsigned short* wl  = (unsigned short*)alloc(NW * 2);
  unsigned short* wph = (unsigned short*)alloc(NWP * 2);
  unsigned short* wpl = (unsigned short*)alloc(NWP * 2);
  unsigned short* hh  = (unsigned short*)alloc(NH * 2);

  // x: split + partial pool in one pass over x
  split_pool_x<<<dim3(16, BATCH), 192, 0, stream>>>(x, xh, xl, partial);
  // w_mfc split (independent)
  split_kernel<<<(int)(NW / 4 / 256), 256, 0, stream>>>(w_mfc, wh, wl, (int)(NW / 4));
  // control path (exact fp32, deterministic)
  pool_final_kernel<<<BATCH, 256, 0, stream>>>(partial, pooled);
  control_kernel<<<BATCH, 256, 0, stream>>>(pooled, w1, w2, ckbuf);
  topk_kernel<<<BATCH, 256, 0, stream>>>(ckbuf, sel);
  // per-batch compacted w_proj operand (direct gather, contiguous axis)
  gather_wp_kernel<<<dim3(KSEL / 256, N_EMBD, BATCH), 256, 0, stream>>>(w_proj, sel, wph, wpl);
  // sparse heavy path on MFMA
  gemm1_mfma<<<dim3(TLEN / 128, KSEL / 128, BATCH), 256, 0, stream>>>(xh, xl, wh, wl, sel, hh);
  gemm2_mfma<<<dim3(TLEN / 128, N_EMBD / 64, BATCH), 256, 0, stream>>>(hh, wph, wpl, out);
}

// Round 4
// 415.815 us; speedup vs baseline: 3.1062x; 1.4881x over previous
//
#include <hip/hip_runtime.h>

#define N_EMBD 768
#define FULL   12288
#define KSEL   3072
#define BATCH  8
#define TLEN   1024
#define HID    48

typedef short bf16x8 __attribute__((ext_vector_type(8)));
typedef float f32x4 __attribute__((ext_vector_type(4)));
typedef unsigned short u16x4 __attribute__((ext_vector_type(4)));
typedef unsigned short u16x8 __attribute__((ext_vector_type(8)));

#define MFMA(a, b, c) __builtin_amdgcn_mfma_f32_16x16x32_bf16((a), (b), (c), 0, 0, 0)
#define GLDS(g, l) __builtin_amdgcn_global_load_lds( \
    (const __attribute__((address_space(1))) void*)(const void*)(g), \
    (__attribute__((address_space(3))) void*)(void*)(l), 16, 0, 0)

__device__ __forceinline__ unsigned short f2bf(float f) {
  unsigned u = __float_as_uint(f);
  u += 0x7fffu + ((u >> 16) & 1u);   // round-to-nearest-even
  return (unsigned short)(u >> 16);
}
__device__ __forceinline__ float bf2f(unsigned short h) {
  return __uint_as_float(((unsigned)h) << 16);
}

// ---------------- fused: split x -> bf16 hi/lo + partial pooling ----------------
// Same t-summation order as the original 2-stage pooling (bit-identical pooled).
__global__ void split_pool_x(const float* __restrict__ x, unsigned short* __restrict__ xh,
                             unsigned short* __restrict__ xl, float* __restrict__ partial) {
  const int s = blockIdx.x;   // 0..15 t-chunk of 64
  const int b = blockIdx.y;
  const int d = threadIdx.x * 4;
  const float* base = x + ((size_t)(b * TLEN + s * 64)) * N_EMBD + d;
  float4 sum = {0.f, 0.f, 0.f, 0.f};
  for (int t = 0; t < 64; ++t) {
    const float4 v = *(const float4*)(base + (size_t)t * N_EMBD);
    sum.x += v.x; sum.y += v.y; sum.z += v.z; sum.w += v.w;
    u16x4 h, l;
    h.x = f2bf(v.x); l.x = f2bf(v.x - bf2f(h.x));
    h.y = f2bf(v.y); l.y = f2bf(v.y - bf2f(h.y));
    h.z = f2bf(v.z); l.z = f2bf(v.z - bf2f(h.z));
    h.w = f2bf(v.w); l.w = f2bf(v.w - bf2f(h.w));
    const size_t o = ((size_t)(b * TLEN + s * 64 + t)) * N_EMBD + d;
    *(u16x4*)(xh + o) = h;
    *(u16x4*)(xl + o) = l;
  }
  float* pp = partial + (b * 16 + s) * N_EMBD + d;
  pp[0] = sum.x; pp[1] = sum.y; pp[2] = sum.z; pp[3] = sum.w;
}

__global__ void pool_final_kernel(const float* __restrict__ partial, float* __restrict__ pooled) {
  const int b = blockIdx.x;
  const int tid = threadIdx.x;
  for (int d = tid; d < N_EMBD; d += 256) {
    float sum = 0.f;
    #pragma unroll
    for (int s = 0; s < 16; ++s) sum += partial[(b * 16 + s) * N_EMBD + d];
    pooled[b * N_EMBD + d] = sum * (1.f / TLEN);
  }
}

// ---------------- control1: hid[b][i] = relu(dot(pooled[b], w1[i])) ----------------
// One thread per (b,i); serial d-loop keeps the exact FP order of the previous rounds.
__global__ void control1_kernel(const float* __restrict__ pooled, const float* __restrict__ w1,
                                float* __restrict__ hid) {
  const int gid = blockIdx.x * 192 + threadIdx.x;   // 0..383
  const int b = gid / HID, i = gid % HID;
  const float* pr = pooled + b * N_EMBD;
  const float* wr = w1 + i * N_EMBD;
  float acc = 0.f;
  #pragma unroll 8
  for (int d = 0; d < N_EMBD; ++d) acc = fmaf(pr[d], wr[d], acc);
  hid[b * HID + i] = fmaxf(acc, 0.f);
}

// ---------------- control2: ck[b][f] = dot(hid[b], w2[f]) ----------------
// grid (FULL/256, BATCH); serial j-loop keeps the exact FP order.
__global__ void control2_kernel(const float* __restrict__ hid, const float* __restrict__ w2,
                                float* __restrict__ ck) {
  const int b = blockIdx.y;
  const int f = blockIdx.x * 256 + threadIdx.x;
  __shared__ float hid_s[HID];
  if (threadIdx.x < HID) hid_s[threadIdx.x] = hid[b * HID + threadIdx.x];
  __syncthreads();
  const float* wr = w2 + (size_t)f * HID;
  float acc = 0.f;
  #pragma unroll
  for (int j = 0; j < HID; ++j) acc = fmaf(hid_s[j], wr[j], acc);
  ck[b * FULL + f] = acc;
}

// ---------------- top-K selection (radix select, keys in registers) ----------------
__global__ void topk_kernel(const float* __restrict__ ck, int* __restrict__ sel) {
  const int b = blockIdx.x;
  const int tid = threadIdx.x;               // 256
  const int lane = tid & 63, wv = tid >> 6;
  unsigned key[48];
  const int f_lo = tid * 48;
  #pragma unroll
  for (int i = 0; i < 48; ++i) {
    unsigned u = __float_as_uint(ck[b * FULL + f_lo + i]);
    key[i] = (u & 0x80000000u) ? ~u : (u | 0x80000000u);  // order-preserving map
  }
  __shared__ unsigned redw[4];
  __shared__ int sg[257], se[257];
  unsigned prefix = 0;
  int remaining = KSEL;
  for (int bit = 31; bit >= 0; --bit) {
    const unsigned want = prefix | (1u << bit);
    const unsigned shifted = want >> bit;
    int cnt = 0;
    #pragma unroll
    for (int i = 0; i < 48; ++i) cnt += ((key[i] >> bit) == shifted) ? 1 : 0;
    #pragma unroll
    for (int off = 1; off < 64; off <<= 1) cnt += __shfl_xor(cnt, off, 64);
    if (lane == 0) redw[wv] = (unsigned)cnt;
    __syncthreads();
    const int c = (int)(redw[0] + redw[1] + redw[2] + redw[3]);
    __syncthreads();
    if (c >= remaining) prefix = want;
    else remaining -= c;
  }
  const unsigned kth = prefix;
  int cg = 0, ce = 0;
  #pragma unroll
  for (int i = 0; i < 48; ++i) { cg += (key[i] > kth) ? 1 : 0; ce += (key[i] == kth) ? 1 : 0; }
  sg[tid] = cg; se[tid] = ce;
  __syncthreads();
  if (tid == 0) {
    int ag = 0, ae = 0;
    for (int i = 0; i < 256; ++i) {
      int tg = sg[i], te = se[i];
      sg[i] = ag; se[i] = ae;
      ag += tg; ae += te;
    }
    sg[256] = ag;
  }
  __syncthreads();
  const int ng = sg[256];
  int gpos = sg[tid], epos = se[tid];
  #pragma unroll
  for (int i = 0; i < 48; ++i) {
    const unsigned k = key[i];
    const int f = f_lo + i;
    if (k > kth) {
      sel[b * KSEL + (gpos++)] = f;
    } else if (k == kth) {
      const int p = ng + epos;
      if (p < KSEL) sel[b * KSEL + p] = f;
      ++epos;
    }
  }
}

// ---------------- fp32 -> bf16 round (w_mfc, hi only) ----------------
__global__ void round_w_kernel(const float* __restrict__ src, unsigned short* __restrict__ dst, int n4) {
  const int idx = blockIdx.x * 256 + threadIdx.x;
  if (idx >= n4) return;
  const float4 v = ((const float4*)src)[idx];
  u16x4 h;
  h.x = f2bf(v.x); h.y = f2bf(v.y); h.z = f2bf(v.z); h.w = f2bf(v.w);
  ((u16x4*)dst)[idx] = h;
}

// ---------------- gather w_proj -> wp[b][e][kk] bf16 (hi only) ----------------
__global__ void gather_wp_kernel(const float* __restrict__ wproj, const int* __restrict__ sel,
                                 unsigned short* __restrict__ wph) {
  const int kk = blockIdx.x * 256 + threadIdx.x;   // 0..3071
  const int e  = blockIdx.y;                       // 0..767
  const int b  = blockIdx.z;
  const int f = sel[b * KSEL + kk];
  wph[((size_t)(b * N_EMBD + e)) * KSEL + kk] = f2bf(wproj[(size_t)e * FULL + f]);
}

// ---------------- GEMM1 (MFMA 2-product, dbuf): h = relu((xh+xl) @ gather(bf16(w_mfc), sel)^T) ----
// 128x128 tile, BK=32, 4 waves (2x2 of 64x64). 48KB LDS (2 x {Axh 8K | Axl 8K | Bwh 8K}).
__global__ __launch_bounds__(256) void gemm1_mfma(
    const unsigned short* __restrict__ xh, const unsigned short* __restrict__ xl,
    const unsigned short* __restrict__ wh, const int* __restrict__ sel,
    unsigned short* __restrict__ hh) {
  __shared__ __align__(16) char sm[49152];
  const int nx = TLEN / 128, ny = KSEL / 128;          // 8, 24
  const int nwg = nx * ny * BATCH;                     // 1536 (divisible by 8)
  int lin = blockIdx.x + nx * (blockIdx.y + ny * blockIdx.z);
  int swz = (lin & 7) * (nwg >> 3) + (lin >> 3);       // XCD-contiguous chunks
  const int bx = swz % nx; int tmp = swz / nx;
  const int by = tmp % ny; const int b = tmp / ny;
  const int t0 = bx * 128, f0 = by * 128;

  const int tid = threadIdx.x;
  const int wv = tid >> 6, lane = tid & 63;
  const int srow = tid >> 2, sslot = tid & 3;
  const int wb = wv * 1024;

  const char* pxh = (const char*)xh;
  const char* pxl = (const char*)xl;
  const char* pwh = (const char*)wh;
  const size_t aoff  = ((size_t)(b * TLEN + t0 + srow)) * 1536 + sslot * 16;  // row stride 768*2B
  const size_t aoff2 = aoff + (size_t)64 * 1536;
  const int* selb = sel + b * KSEL;
  const size_t boff  = (size_t)selb[f0 + srow] * 1536 + sslot * 16;
  const size_t boff2 = (size_t)selb[f0 + srow + 64] * 1536 + sslot * 16;

  const int fr = lane & 15, kg = lane >> 4;
  const int fo = fr * 64 + kg * 16;
  const int m0 = (wv >> 1) * 64, n0 = (wv & 1) * 64;

  f32x4 acc[4][4];
  const f32x4 z4 = {0.f, 0.f, 0.f, 0.f};
  #pragma unroll
  for (int mi = 0; mi < 4; ++mi)
    #pragma unroll
    for (int ni = 0; ni < 4; ++ni) acc[mi][ni] = z4;

  auto stage = [&](int bo, int d) {
    GLDS(pxh + aoff  + d, sm + bo + 0     + wb);
    GLDS(pxh + aoff2 + d, sm + bo + 4096  + wb);
    GLDS(pxl + aoff  + d, sm + bo + 8192  + wb);
    GLDS(pxl + aoff2 + d, sm + bo + 12288 + wb);
    GLDS(pwh + boff  + d, sm + bo + 16384 + wb);
    GLDS(pwh + boff2 + d, sm + bo + 20480 + wb);
  };
  stage(0, 0);
  __syncthreads();
  const int NIT = N_EMBD * 2 / 64;   // 24
  for (int it = 0; it < NIT; ++it) {
    const int cur = (it & 1) ? 24576 : 0;
    if (it + 1 < NIT) stage(cur ^ 24576, (it + 1) * 64);
    bf16x8 ah[4], al[4], bh[4];
    #pragma unroll
    for (int i = 0; i < 4; ++i) {
      const int ra = (m0 + i * 16) * 64 + fo;
      const int rb = (n0 + i * 16) * 64 + fo;
      ah[i] = *(const bf16x8*)(sm + cur + 0     + ra);
      al[i] = *(const bf16x8*)(sm + cur + 8192  + ra);
      bh[i] = *(const bf16x8*)(sm + cur + 16384 + rb);
    }
    #pragma unroll
    for (int mi = 0; mi < 4; ++mi)
      #pragma unroll
      for (int ni = 0; ni < 4; ++ni) {
        acc[mi][ni] = MFMA(ah[mi], bh[ni], acc[mi][ni]);
        acc[mi][ni] = MFMA(al[mi], bh[ni], acc[mi][ni]);
      }
    __syncthreads();
  }
  // epilogue: relu -> bf16, repack through LDS, coalesced 16B stores.
  unsigned short* lh = (unsigned short*)sm;  // [128][128] bf16 = 32KB (fits in 48K)
  const int rowg = lane >> 4, colc = lane & 15;
  #pragma unroll
  for (int mi = 0; mi < 4; ++mi)
    #pragma unroll
    for (int ni = 0; ni < 4; ++ni) {
      const int row = m0 + mi * 16 + rowg * 4;
      const int col = n0 + ni * 16 + colc;
      #pragma unroll
      for (int j = 0; j < 4; ++j)
        lh[(row + j) * 128 + col] = f2bf(fmaxf(acc[mi][ni][j], 0.f));
    }
  __syncthreads();
  const int orow = tid >> 4, oc = tid & 15;
  #pragma unroll
  for (int i2 = 0; i2 < 8; ++i2) {
    const int row = orow + i2 * 16;
    const u16x8 v = *(const u16x8*)&lh[row * 128 + oc * 8];
    *(u16x8*)(hh + ((size_t)(b * TLEN + t0 + row)) * KSEL + f0 + oc * 8) = v;
  }
}

// ---------------- GEMM2 (MFMA 1-product, BK=64 dual-chunk, dbuf): out = hh @ wph^T ----------------
// 128x64 tile, 4 waves (2x2 of 64x32). 48KB LDS (2 x {A0 8K | A1 8K | B0 4K | B1 4K}).
__global__ __launch_bounds__(256) void gemm2_mfma(
    const unsigned short* __restrict__ hh, const unsigned short* __restrict__ wph,
    float* __restrict__ out) {
  __shared__ __align__(16) char sm[49152];
  const int nx = TLEN / 128, ny = N_EMBD / 64;         // 8, 12
  const int nwg = nx * ny * BATCH;                     // 768
  int lin = blockIdx.x + nx * (blockIdx.y + ny * blockIdx.z);
  int swz = (lin & 7) * (nwg >> 3) + (lin >> 3);
  const int bx = swz % nx; int tmp = swz / nx;
  const int by = tmp % ny; const int b = tmp / ny;
  const int t0 = bx * 128, e0 = by * 64;

  const int tid = threadIdx.x;
  const int wv = tid >> 6, lane = tid & 63;
  const int wb = wv * 1024;

  const char* pa = (const char*)hh;
  const char* pb = (const char*)wph;
  const size_t aoff  = ((size_t)(b * TLEN + t0 + (tid >> 2))) * 6144 + (tid & 3) * 16;
  const size_t aoff2 = aoff + (size_t)64 * 6144;
  const size_t boff  = ((size_t)(b * N_EMBD + e0 + (tid >> 2))) * 6144 + (tid & 3) * 16;

  const int fr = lane & 15, kg = lane >> 4;
  const int fo = fr * 64 + kg * 16;
  const int m0 = (wv >> 1) * 64, n0 = (wv & 1) * 32;

  f32x4 acc[4][2];
  const f32x4 z4 = {0.f, 0.f, 0.f, 0.f};
  #pragma unroll
  for (int mi = 0; mi < 4; ++mi)
    #pragma unroll
    for (int ni = 0; ni < 2; ++ni) acc[mi][ni] = z4;

  auto stage = [&](int bo, int d) {
    GLDS(pa + aoff  + d,      sm + bo + 0     + wb);   // A rows 0-63,  k-chunk 0
    GLDS(pa + aoff2 + d,      sm + bo + 4096  + wb);   // A rows 64-127, chunk 0
    GLDS(pa + aoff  + d + 64, sm + bo + 8192  + wb);   // A rows 0-63,  chunk 1
    GLDS(pa + aoff2 + d + 64, sm + bo + 12288 + wb);   // A rows 64-127, chunk 1
    GLDS(pb + boff  + d,      sm + bo + 16384 + wb);   // B chunk 0
    GLDS(pb + boff  + d + 64, sm + bo + 20480 + wb);   // B chunk 1
  };
  stage(0, 0);
  __syncthreads();
  const int NIT = KSEL * 2 / 128;        // 48
  for (int it = 0; it < NIT; ++it) {
    const int cur = (it & 1) ? 24576 : 0;
    if (it + 1 < NIT) stage(cur ^ 24576, (it + 1) * 128);
    bf16x8 ah[4][2], bh[2][2];
    #pragma unroll
    for (int i = 0; i < 4; ++i) {
      const int ra = (m0 + i * 16) * 64 + fo;
      ah[i][0] = *(const bf16x8*)(sm + cur + 0    + ra);
      ah[i][1] = *(const bf16x8*)(sm + cur + 8192 + ra);
    }
    #pragma unroll
    for (int i = 0; i < 2; ++i) {
      const int rb = (n0 + i * 16) * 64 + fo;
      bh[i][0] = *(const bf16x8*)(sm + cur + 16384 + rb);
      bh[i][1] = *(const bf16x8*)(sm + cur + 20480 + rb);
    }
    #pragma unroll
    for (int c = 0; c < 2; ++c)
      #pragma unroll
      for (int mi = 0; mi < 4; ++mi)
        #pragma unroll
        for (int ni = 0; ni < 2; ++ni)
          acc[mi][ni] = MFMA(ah[mi][c], bh[ni][c], acc[mi][ni]);
    __syncthreads();
  }
  const int rowg = lane >> 4, colc = lane & 15;
  #pragma unroll
  for (int mi = 0; mi < 4; ++mi)
    #pragma unroll
    for (int ni = 0; ni < 2; ++ni) {
      const int m = t0 + m0 + mi * 16 + rowg * 4;
      const int e = e0 + n0 + ni * 16 + colc;
      const size_t base = ((size_t)(b * TLEN + m)) * N_EMBD + e;
      #pragma unroll
      for (int j = 0; j < 4; ++j)
        out[base + (size_t)j * N_EMBD] = acc[mi][ni][j];
    }
}

// ---------------- launch ----------------
extern "C" void kernel_launch(void* const* d_in, const int* in_sizes, int n_in,
                              void* d_out, int out_size, void* d_ws, size_t ws_size,
                              hipStream_t stream) {
  const float* x      = (const float*)d_in[0];
  const float* w1     = (const float*)d_in[1];
  const float* w2     = (const float*)d_in[2];
  const float* w_mfc  = (const float*)d_in[3];
  const float* w_proj = (const float*)d_in[4];
  float* out = (float*)d_out;

  char* ws = (char*)d_ws;
  size_t off = 0;
  auto alloc = [&](size_t bytes) -> void* {
    void* p = ws + off;
    off += (bytes + 255) & ~(size_t)255;
    return p;
  };
  const size_t NX  = (size_t)BATCH * TLEN * N_EMBD;   // 6,291,456
  const size_t NW  = (size_t)FULL * N_EMBD;           // 9,437,184
  const size_t NWP = (size_t)BATCH * N_EMBD * KSEL;   // 18,874,368
  const size_t NH  = (size_t)BATCH * TLEN * KSEL;     // 25,165,824

  float* partial = (float*)alloc((size_t)BATCH * 16 * N_EMBD * 4);
  float* pooled  = (float*)alloc((size_t)BATCH * N_EMBD * 4);
  float* hid     = (float*)alloc((size_t)BATCH * HID * 4);
  float* ckbuf   = (float*)alloc((size_t)BATCH * FULL * 4);
  int*   sel     = (int*)  alloc((size_t)BATCH * KSEL * 4);
  unsigned short* xh  = (unsigned short*)alloc(NX * 2);
  unsigned short* xl  = (unsigned short*)alloc(NX * 2);
  unsigned short* wh  = (unsigned short*)alloc(NW * 2);
  unsigned short* wph = (unsigned short*)alloc(NWP * 2);
  unsigned short* hh  = (unsigned short*)alloc(NH * 2);

  // x: split + partial pool in one pass over x (t-order identical to prior rounds)
  split_pool_x<<<dim3(16, BATCH), 192, 0, stream>>>(x, xh, xl, partial);
  // w_mfc round to bf16 (independent)
  round_w_kernel<<<(int)(NW / 4 / 256), 256, 0, stream>>>(w_mfc, wh, (int)(NW / 4));
  // control path (exact fp32, FP-order-identical to prior rounds -> same sel)
  pool_final_kernel<<<BATCH, 256, 0, stream>>>(partial, pooled);
  control1_kernel<<<2, 192, 0, stream>>>(pooled, w1, hid);
  control2_kernel<<<dim3(FULL / 256, BATCH), 256, 0, stream>>>(hid, w2, ckbuf);
  topk_kernel<<<BATCH, 256, 0, stream>>>(ckbuf, sel);
  // per-batch compacted w_proj operand (bf16 hi only)
  gather_wp_kernel<<<dim3(KSEL / 256, N_EMBD, BATCH), 256, 0, stream>>>(w_proj, sel, wph);
  // sparse heavy path on MFMA
  gemm1_mfma<<<dim3(TLEN / 128, KSEL / 128, BATCH), 256, 0, stream>>>(xh, xl, wh, sel, hh);
  gemm2_mfma<<<dim3(TLEN / 128, N_EMBD / 64, BATCH), 256, 0, stream>>>(hh, wph, out);
}

// Round 5
// 395.426 us; speedup vs baseline: 3.2664x; 1.0516x over previous
//
#include <hip/hip_runtime.h>

#define N_EMBD 768
#define FULL   12288
#define KSEL   3072
#define BATCH  8
#define TLEN   1024
#define HID    48

typedef short bf16x8 __attribute__((ext_vector_type(8)));
typedef float f32x4 __attribute__((ext_vector_type(4)));
typedef unsigned short u16x4 __attribute__((ext_vector_type(4)));
typedef unsigned short u16x8 __attribute__((ext_vector_type(8)));

#define MFMA(a, b, c) __builtin_amdgcn_mfma_f32_16x16x32_bf16((a), (b), (c), 0, 0, 0)
#define GLDS(g, l) __builtin_amdgcn_global_load_lds( \
    (const __attribute__((address_space(1))) void*)(const void*)(g), \
    (__attribute__((address_space(3))) void*)(void*)(l), 16, 0, 0)

__device__ __forceinline__ unsigned short f2bf(float f) {
  unsigned u = __float_as_uint(f);
  u += 0x7fffu + ((u >> 16) & 1u);   // round-to-nearest-even
  return (unsigned short)(u >> 16);
}
__device__ __forceinline__ float bf2f(unsigned short h) {
  return __uint_as_float(((unsigned)h) << 16);
}

// ---------------- fused: split x -> bf16 hi/lo + partial pooling ----------------
// d-axis split across blockIdx.z; each d's 64-t serial sum order is unchanged
// vs all prior rounds -> bit-identical partial/pooled -> identical top-k.
__global__ void split_pool_x(const float* __restrict__ x, unsigned short* __restrict__ xh,
                             unsigned short* __restrict__ xl, float* __restrict__ partial) {
  const int s = blockIdx.x;   // 0..15 t-chunk of 64
  const int b = blockIdx.y;
  const int d = blockIdx.z * 256 + threadIdx.x * 4;   // z: 0..2, tid: 0..63
  const float* base = x + ((size_t)(b * TLEN + s * 64)) * N_EMBD + d;
  float4 sum = {0.f, 0.f, 0.f, 0.f};
  for (int t = 0; t < 64; ++t) {
    const float4 v = *(const float4*)(base + (size_t)t * N_EMBD);
    sum.x += v.x; sum.y += v.y; sum.z += v.z; sum.w += v.w;
    u16x4 h, l;
    h.x = f2bf(v.x); l.x = f2bf(v.x - bf2f(h.x));
    h.y = f2bf(v.y); l.y = f2bf(v.y - bf2f(h.y));
    h.z = f2bf(v.z); l.z = f2bf(v.z - bf2f(h.z));
    h.w = f2bf(v.w); l.w = f2bf(v.w - bf2f(h.w));
    const size_t o = ((size_t)(b * TLEN + s * 64 + t)) * N_EMBD + d;
    *(u16x4*)(xh + o) = h;
    *(u16x4*)(xl + o) = l;
  }
  float* pp = partial + (b * 16 + s) * N_EMBD + d;
  pp[0] = sum.x; pp[1] = sum.y; pp[2] = sum.z; pp[3] = sum.w;
}

__global__ void pool_final_kernel(const float* __restrict__ partial, float* __restrict__ pooled) {
  const int b = blockIdx.x;
  const int tid = threadIdx.x;
  for (int d = tid; d < N_EMBD; d += 256) {
    float sum = 0.f;
    #pragma unroll
    for (int s = 0; s < 16; ++s) sum += partial[(b * 16 + s) * N_EMBD + d];
    pooled[b * N_EMBD + d] = sum * (1.f / TLEN);
  }
}

// ---------------- control1: hid[b][i] = relu(dot(pooled[b], w1[i])) ----------------
// One block per b. w1 staged to LDS in two d-halves (coalesced); the 48 dot-lanes
// accumulate one ascending-d fmaf chain across both halves -> bit-identical to the
// previous serial per-thread loop. LDS row stride 385 kills the 48-way bank conflict.
__global__ __launch_bounds__(256) void control1_kernel(
    const float* __restrict__ pooled, const float* __restrict__ w1, float* __restrict__ hid) {
  __shared__ float w1s[HID][385];   // 73.9 KB
  __shared__ float ps[N_EMBD];
  const int b = blockIdx.x;
  const int tid = threadIdx.x;
  for (int d = tid; d < N_EMBD; d += 256) ps[d] = pooled[b * N_EMBD + d];
  float acc = 0.f;
  #pragma unroll
  for (int half = 0; half < 2; ++half) {
    __syncthreads();                 // guards ps (half 0) and w1s reuse (half 1)
    for (int i = tid; i < HID * 384; i += 256) {
      const int r = i / 384, c = i % 384;
      w1s[r][c] = w1[r * N_EMBD + half * 384 + c];
    }
    __syncthreads();
    if (tid < HID) {
      const float* pr = ps + half * 384;
      #pragma unroll 8
      for (int d2 = 0; d2 < 384; ++d2) acc = fmaf(pr[d2], w1s[tid][d2], acc);
    }
  }
  if (tid < HID) hid[b * HID + tid] = fmaxf(acc, 0.f);
}

// ---------------- control2: ck[b][f] = dot(hid[b], w2[f]) ----------------
__global__ void control2_kernel(const float* __restrict__ hid, const float* __restrict__ w2,
                                float* __restrict__ ck) {
  const int b = blockIdx.y;
  const int f = blockIdx.x * 256 + threadIdx.x;
  __shared__ float hid_s[HID];
  if (threadIdx.x < HID) hid_s[threadIdx.x] = hid[b * HID + threadIdx.x];
  __syncthreads();
  const float* wr = w2 + (size_t)f * HID;
  float acc = 0.f;
  #pragma unroll
  for (int j = 0; j < HID; ++j) acc = fmaf(hid_s[j], wr[j], acc);
  ck[b * FULL + f] = acc;
}

// ---------------- top-K selection (radix select, keys in registers) ----------------
__global__ void topk_kernel(const float* __restrict__ ck, int* __restrict__ sel) {
  const int b = blockIdx.x;
  const int tid = threadIdx.x;               // 256
  const int lane = tid & 63, wv = tid >> 6;
  unsigned key[48];
  const int f_lo = tid * 48;
  #pragma unroll
  for (int i = 0; i < 48; ++i) {
    unsigned u = __float_as_uint(ck[b * FULL + f_lo + i]);
    key[i] = (u & 0x80000000u) ? ~u : (u | 0x80000000u);  // order-preserving map
  }
  __shared__ unsigned redw[4];
  __shared__ int sg[257], se[257];
  unsigned prefix = 0;
  int remaining = KSEL;
  for (int bit = 31; bit >= 0; --bit) {
    const unsigned want = prefix | (1u << bit);
    const unsigned shifted = want >> bit;
    int cnt = 0;
    #pragma unroll
    for (int i = 0; i < 48; ++i) cnt += ((key[i] >> bit) == shifted) ? 1 : 0;
    #pragma unroll
    for (int off = 1; off < 64; off <<= 1) cnt += __shfl_xor(cnt, off, 64);
    if (lane == 0) redw[wv] = (unsigned)cnt;
    __syncthreads();
    const int c = (int)(redw[0] + redw[1] + redw[2] + redw[3]);
    __syncthreads();
    if (c >= remaining) prefix = want;
    else remaining -= c;
  }
  const unsigned kth = prefix;
  int cg = 0, ce = 0;
  #pragma unroll
  for (int i = 0; i < 48; ++i) { cg += (key[i] > kth) ? 1 : 0; ce += (key[i] == kth) ? 1 : 0; }
  sg[tid] = cg; se[tid] = ce;
  __syncthreads();
  if (tid == 0) {
    int ag = 0, ae = 0;
    for (int i = 0; i < 256; ++i) {
      int tg = sg[i], te = se[i];
      sg[i] = ag; se[i] = ae;
      ag += tg; ae += te;
    }
    sg[256] = ag;
  }
  __syncthreads();
  const int ng = sg[256];
  int gpos = sg[tid], epos = se[tid];
  #pragma unroll
  for (int i = 0; i < 48; ++i) {
    const unsigned k = key[i];
    const int f = f_lo + i;
    if (k > kth) {
      sel[b * KSEL + (gpos++)] = f;
    } else if (k == kth) {
      const int p = ng + epos;
      if (p < KSEL) sel[b * KSEL + p] = f;
      ++epos;
    }
  }
}

// ---------------- fp32 -> bf16 round (w_mfc, hi only) ----------------
__global__ void round_w_kernel(const float* __restrict__ src, unsigned short* __restrict__ dst, int n4) {
  const int idx = blockIdx.x * 256 + threadIdx.x;
  if (idx >= n4) return;
  const float4 v = ((const float4*)src)[idx];
  u16x4 h;
  h.x = f2bf(v.x); h.y = f2bf(v.y); h.z = f2bf(v.z); h.w = f2bf(v.w);
  ((u16x4*)dst)[idx] = h;
}

// ---------------- gather w_proj -> wp[b][e][kk] bf16 (hi only) ----------------
// 384 blocks; sel cached in LDS; 16B vectorized stores (8 gathers/thread/chunk).
__global__ __launch_bounds__(256) void gather_wp_kernel(
    const float* __restrict__ wproj, const int* __restrict__ sel,
    unsigned short* __restrict__ wph) {
  __shared__ int sel_s[KSEL];   // 12 KB
  const int eg = blockIdx.x;    // 0..47 -> 16 e-rows each
  const int b  = blockIdx.y;
  const int tid = threadIdx.x;
  for (int i = tid; i < KSEL; i += 256) sel_s[i] = sel[b * KSEL + i];
  __syncthreads();
  for (int e = eg * 16; e < eg * 16 + 16; ++e) {
    const float* wr = wproj + (size_t)e * FULL;
    unsigned short* orow = wph + ((size_t)(b * N_EMBD + e)) * KSEL;
    for (int c = tid; c < KSEL / 8; c += 256) {
      const int k0 = c * 8;
      u16x8 v;
      #pragma unroll
      for (int j = 0; j < 8; ++j) v[j] = f2bf(wr[sel_s[k0 + j]]);
      *(u16x8*)(orow + k0) = v;
    }
  }
}

// ---------------- GEMM1 (MFMA 2-product, dbuf): h = relu((xh+xl) @ gather(bf16(w_mfc), sel)^T) ----
// 128x128 tile, BK=32, 4 waves (2x2 of 64x64). 48KB LDS (2 x {Axh 8K | Axl 8K | Bwh 8K}).
__global__ __launch_bounds__(256) void gemm1_mfma(
    const unsigned short* __restrict__ xh, const unsigned short* __restrict__ xl,
    const unsigned short* __restrict__ wh, const int* __restrict__ sel,
    unsigned short* __restrict__ hh) {
  __shared__ __align__(16) char sm[49152];
  const int nx = TLEN / 128, ny = KSEL / 128;          // 8, 24
  const int nwg = nx * ny * BATCH;                     // 1536 (divisible by 8)
  int lin = blockIdx.x + nx * (blockIdx.y + ny * blockIdx.z);
  int swz = (lin & 7) * (nwg >> 3) + (lin >> 3);       // XCD-contiguous chunks
  const int bx = swz % nx; int tmp = swz / nx;
  const int by = tmp % ny; const int b = tmp / ny;
  const int t0 = bx * 128, f0 = by * 128;

  const int tid = threadIdx.x;
  const int wv = tid >> 6, lane = tid & 63;
  const int srow = tid >> 2, sslot = tid & 3;
  const int wb = wv * 1024;

  const char* pxh = (const char*)xh;
  const char* pxl = (const char*)xl;
  const char* pwh = (const char*)wh;
  const size_t aoff  = ((size_t)(b * TLEN + t0 + srow)) * 1536 + sslot * 16;  // row stride 768*2B
  const size_t aoff2 = aoff + (size_t)64 * 1536;
  const int* selb = sel + b * KSEL;
  const size_t boff  = (size_t)selb[f0 + srow] * 1536 + sslot * 16;
  const size_t boff2 = (size_t)selb[f0 + srow + 64] * 1536 + sslot * 16;

  const int fr = lane & 15, kg = lane >> 4;
  const int fo = fr * 64 + kg * 16;
  const int m0 = (wv >> 1) * 64, n0 = (wv & 1) * 64;

  f32x4 acc[4][4];
  const f32x4 z4 = {0.f, 0.f, 0.f, 0.f};
  #pragma unroll
  for (int mi = 0; mi < 4; ++mi)
    #pragma unroll
    for (int ni = 0; ni < 4; ++ni) acc[mi][ni] = z4;

  auto stage = [&](int bo, int d) {
    GLDS(pxh + aoff  + d, sm + bo + 0     + wb);
    GLDS(pxh + aoff2 + d, sm + bo + 4096  + wb);
    GLDS(pxl + aoff  + d, sm + bo + 8192  + wb);
    GLDS(pxl + aoff2 + d, sm + bo + 12288 + wb);
    GLDS(pwh + boff  + d, sm + bo + 16384 + wb);
    GLDS(pwh + boff2 + d, sm + bo + 20480 + wb);
  };
  stage(0, 0);
  __syncthreads();
  const int NIT = N_EMBD * 2 / 64;   // 24
  for (int it = 0; it < NIT; ++it) {
    const int cur = (it & 1) ? 24576 : 0;
    if (it + 1 < NIT) stage(cur ^ 24576, (it + 1) * 64);
    bf16x8 ah[4], al[4], bh[4];
    #pragma unroll
    for (int i = 0; i < 4; ++i) {
      const int ra = (m0 + i * 16) * 64 + fo;
      const int rb = (n0 + i * 16) * 64 + fo;
      ah[i] = *(const bf16x8*)(sm + cur + 0     + ra);
      al[i] = *(const bf16x8*)(sm + cur + 8192  + ra);
      bh[i] = *(const bf16x8*)(sm + cur + 16384 + rb);
    }
    #pragma unroll
    for (int mi = 0; mi < 4; ++mi)
      #pragma unroll
      for (int ni = 0; ni < 4; ++ni) {
        acc[mi][ni] = MFMA(ah[mi], bh[ni], acc[mi][ni]);
        acc[mi][ni] = MFMA(al[mi], bh[ni], acc[mi][ni]);
      }
    __syncthreads();
  }
  // epilogue: relu -> bf16, repack through LDS, coalesced 16B stores.
  unsigned short* lh = (unsigned short*)sm;  // [128][128] bf16 = 32KB (fits in 48K)
  const int rowg = lane >> 4, colc = lane & 15;
  #pragma unroll
  for (int mi = 0; mi < 4; ++mi)
    #pragma unroll
    for (int ni = 0; ni < 4; ++ni) {
      const int row = m0 + mi * 16 + rowg * 4;
      const int col = n0 + ni * 16 + colc;
      #pragma unroll
      for (int j = 0; j < 4; ++j)
        lh[(row + j) * 128 + col] = f2bf(fmaxf(acc[mi][ni][j], 0.f));
    }
  __syncthreads();
  const int orow = tid >> 4, oc = tid & 15;
  #pragma unroll
  for (int i2 = 0; i2 < 8; ++i2) {
    const int row = orow + i2 * 16;
    const u16x8 v = *(const u16x8*)&lh[row * 128 + oc * 8];
    *(u16x8*)(hh + ((size_t)(b * TLEN + t0 + row)) * KSEL + f0 + oc * 8) = v;
  }
}

// ---------------- GEMM2 (MFMA 1-product, BK=64 dual-chunk, dbuf): out = hh @ wph^T ----------------
// 128x64 tile, 4 waves (2x2 of 64x32). 48KB LDS (2 x {A0 8K | A1 8K | B0 4K | B1 4K}).
__global__ __launch_bounds__(256) void gemm2_mfma(
    const unsigned short* __restrict__ hh, const unsigned short* __restrict__ wph,
    float* __restrict__ out) {
  __shared__ __align__(16) char sm[49152];
  const int nx = TLEN / 128, ny = N_EMBD / 64;         // 8, 12
  const int nwg = nx * ny * BATCH;                     // 768
  int lin = blockIdx.x + nx * (blockIdx.y + ny * blockIdx.z);
  int swz = (lin & 7) * (nwg >> 3) + (lin >> 3);
  const int bx = swz % nx; int tmp = swz / nx;
  const int by = tmp % ny; const int b = tmp / ny;
  const int t0 = bx * 128, e0 = by * 64;

  const int tid = threadIdx.x;
  const int wv = tid >> 6, lane = tid & 63;
  const int wb = wv * 1024;

  const char* pa = (const char*)hh;
  const char* pb = (const char*)wph;
  const size_t aoff  = ((size_t)(b * TLEN + t0 + (tid >> 2))) * 6144 + (tid & 3) * 16;
  const size_t aoff2 = aoff + (size_t)64 * 6144;
  const size_t boff  = ((size_t)(b * N_EMBD + e0 + (tid >> 2))) * 6144 + (tid & 3) * 16;

  const int fr = lane & 15, kg = lane >> 4;
  const int fo = fr * 64 + kg * 16;
  const int m0 = (wv >> 1) * 64, n0 = (wv & 1) * 32;

  f32x4 acc[4][2];
  const f32x4 z4 = {0.f, 0.f, 0.f, 0.f};
  #pragma unroll
  for (int mi = 0; mi < 4; ++mi)
    #pragma unroll
    for (int ni = 0; ni < 2; ++ni) acc[mi][ni] = z4;

  auto stage = [&](int bo, int d) {
    GLDS(pa + aoff  + d,      sm + bo + 0     + wb);   // A rows 0-63,  k-chunk 0
    GLDS(pa + aoff2 + d,      sm + bo + 4096  + wb);   // A rows 64-127, chunk 0
    GLDS(pa + aoff  + d + 64, sm + bo + 8192  + wb);   // A rows 0-63,  chunk 1
    GLDS(pa + aoff2 + d + 64, sm + bo + 12288 + wb);   // A rows 64-127, chunk 1
    GLDS(pb + boff  + d,      sm + bo + 16384 + wb);   // B chunk 0
    GLDS(pb + boff  + d + 64, sm + bo + 20480 + wb);   // B chunk 1
  };
  stage(0, 0);
  __syncthreads();
  const int NIT = KSEL * 2 / 128;        // 48
  for (int it = 0; it < NIT; ++it) {
    const int cur = (it & 1) ? 24576 : 0;
    if (it + 1 < NIT) stage(cur ^ 24576, (it + 1) * 128);
    bf16x8 ah[4][2], bh[2][2];
    #pragma unroll
    for (int i = 0; i < 4; ++i) {
      const int ra = (m0 + i * 16) * 64 + fo;
      ah[i][0] = *(const bf16x8*)(sm + cur + 0    + ra);
      ah[i][1] = *(const bf16x8*)(sm + cur + 8192 + ra);
    }
    #pragma unroll
    for (int i = 0; i < 2; ++i) {
      const int rb = (n0 + i * 16) * 64 + fo;
      bh[i][0] = *(const bf16x8*)(sm + cur + 16384 + rb);
      bh[i][1] = *(const bf16x8*)(sm + cur + 20480 + rb);
    }
    #pragma unroll
    for (int c = 0; c < 2; ++c)
      #pragma unroll
      for (int mi = 0; mi < 4; ++mi)
        #pragma unroll
        for (int ni = 0; ni < 2; ++ni)
          acc[mi][ni] = MFMA(ah[mi][c], bh[ni][c], acc[mi][ni]);
    __syncthreads();
  }
  const int rowg = lane >> 4, colc = lane & 15;
  #pragma unroll
  for (int mi = 0; mi < 4; ++mi)
    #pragma unroll
    for (int ni = 0; ni < 2; ++ni) {
      const int m = t0 + m0 + mi * 16 + rowg * 4;
      const int e = e0 + n0 + ni * 16 + colc;
      const size_t base = ((size_t)(b * TLEN + m)) * N_EMBD + e;
      #pragma unroll
      for (int j = 0; j < 4; ++j)
        out[base + (size_t)j * N_EMBD] = acc[mi][ni][j];
    }
}

// ---------------- launch ----------------
extern "C" void kernel_launch(void* const* d_in, const int* in_sizes, int n_in,
                              void* d_out, int out_size, void* d_ws, size_t ws_size,
                              hipStream_t stream) {
  const float* x      = (const float*)d_in[0];
  const float* w1     = (const float*)d_in[1];
  const float* w2     = (const float*)d_in[2];
  const float* w_mfc  = (const float*)d_in[3];
  const float* w_proj = (const float*)d_in[4];
  float* out = (float*)d_out;

  char* ws = (char*)d_ws;
  size_t off = 0;
  auto alloc = [&](size_t bytes) -> void* {
    void* p = ws + off;
    off += (bytes + 255) & ~(size_t)255;
    return p;
  };
  const size_t NX  = (size_t)BATCH * TLEN * N_EMBD;   // 6,291,456
  const size_t NW  = (size_t)FULL * N_EMBD;           // 9,437,184
  const size_t NWP = (size_t)BATCH * N_EMBD * KSEL;   // 18,874,368
  const size_t NH  = (size_t)BATCH * TLEN * KSEL;     // 25,165,824

  float* partial = (float*)alloc((size_t)BATCH * 16 * N_EMBD * 4);
  float* pooled  = (float*)alloc((size_t)BATCH * N_EMBD * 4);
  float* hid     = (float*)alloc((size_t)BATCH * HID * 4);
  float* ckbuf   = (float*)alloc((size_t)BATCH * FULL * 4);
  int*   sel     = (int*)  alloc((size_t)BATCH * KSEL * 4);
  unsigned short* xh  = (unsigned short*)alloc(NX * 2);
  unsigned short* xl  = (unsigned short*)alloc(NX * 2);
  unsigned short* wh  = (unsigned short*)alloc(NW * 2);
  unsigned short* wph = (unsigned short*)alloc(NWP * 2);
  unsigned short* hh  = (unsigned short*)alloc(NH * 2);

  // x: split + partial pool in one pass over x (per-d t-order identical to prior rounds)
  split_pool_x<<<dim3(16, BATCH, 3), 64, 0, stream>>>(x, xh, xl, partial);
  // w_mfc round to bf16 (independent)
  round_w_kernel<<<(int)(NW / 4 / 256), 256, 0, stream>>>(w_mfc, wh, (int)(NW / 4));
  // control path (exact fp32, FP-order-identical to prior rounds -> same sel)
  pool_final_kernel<<<BATCH, 256, 0, stream>>>(partial, pooled);
  control1_kernel<<<BATCH, 256, 0, stream>>>(pooled, w1, hid);
  control2_kernel<<<dim3(FULL / 256, BATCH), 256, 0, stream>>>(hid, w2, ckbuf);
  topk_kernel<<<BATCH, 256, 0, stream>>>(ckbuf, sel);
  // per-batch compacted w_proj operand (bf16 hi only)
  gather_wp_kernel<<<dim3(48, BATCH), 256, 0, stream>>>(w_proj, sel, wph);
  // sparse heavy path on MFMA
  gemm1_mfma<<<dim3(TLEN / 128, KSEL / 128, BATCH), 256, 0, stream>>>(xh, xl, wh, sel, hh);
  gemm2_mfma<<<dim3(TLEN / 128, N_EMBD / 64, BATCH), 256, 0, stream>>>(hh, wph, out);
}

// Round 6
// 382.547 us; speedup vs baseline: 3.3763x; 1.0337x over previous
//
#include <hip/hip_runtime.h>

#define N_EMBD 768
#define FULL   12288
#define KSEL   3072
#define BATCH  8
#define TLEN   1024
#define HID    48

typedef short bf16x8 __attribute__((ext_vector_type(8)));
typedef float f32x4 __attribute__((ext_vector_type(4)));
typedef unsigned short u16x4 __attribute__((ext_vector_type(4)));
typedef unsigned short u16x8 __attribute__((ext_vector_type(8)));

#define MFMA(a, b, c) __builtin_amdgcn_mfma_f32_16x16x32_bf16((a), (b), (c), 0, 0, 0)
#define GLDS(g, l) __builtin_amdgcn_global_load_lds( \
    (const __attribute__((address_space(1))) void*)(const void*)(g), \
    (__attribute__((address_space(3))) void*)(void*)(l), 16, 0, 0)

__device__ __forceinline__ unsigned short f2bf(float f) {
  unsigned u = __float_as_uint(f);
  u += 0x7fffu + ((u >> 16) & 1u);   // round-to-nearest-even
  return (unsigned short)(u >> 16);
}
__device__ __forceinline__ float bf2f(unsigned short h) {
  return __uint_as_float(((unsigned)h) << 16);
}

// ---------------- fused: split x -> bf16 hi/lo + partial pooling ----------------
// Per-d 64-t serial sum order unchanged vs prior rounds -> bit-identical partial.
__global__ void split_pool_x(const float* __restrict__ x, unsigned short* __restrict__ xh,
                             unsigned short* __restrict__ xl, float* __restrict__ partial) {
  const int s = blockIdx.x;   // 0..15 t-chunk of 64
  const int b = blockIdx.y;
  const int d = blockIdx.z * 256 + threadIdx.x * 4;   // z: 0..2, tid: 0..63
  const float* base = x + ((size_t)(b * TLEN + s * 64)) * N_EMBD + d;
  float4 sum = {0.f, 0.f, 0.f, 0.f};
  for (int t = 0; t < 64; ++t) {
    const float4 v = *(const float4*)(base + (size_t)t * N_EMBD);
    sum.x += v.x; sum.y += v.y; sum.z += v.z; sum.w += v.w;
    u16x4 h, l;
    h.x = f2bf(v.x); l.x = f2bf(v.x - bf2f(h.x));
    h.y = f2bf(v.y); l.y = f2bf(v.y - bf2f(h.y));
    h.z = f2bf(v.z); l.z = f2bf(v.z - bf2f(h.z));
    h.w = f2bf(v.w); l.w = f2bf(v.w - bf2f(h.w));
    const size_t o = ((size_t)(b * TLEN + s * 64 + t)) * N_EMBD + d;
    *(u16x4*)(xh + o) = h;
    *(u16x4*)(xl + o) = l;
  }
  float* pp = partial + (b * 16 + s) * N_EMBD + d;
  pp[0] = sum.x; pp[1] = sum.y; pp[2] = sum.z; pp[3] = sum.w;
}

// ---------------- control1 (fused pool_final): hid[b][i] = relu(dot(pooled[b], w1[i])) ----
// pooled computed in LDS with the same ascending-s order as the old pool_final
// -> bit-identical. w1 staged to LDS in two halves; 48 dot-lanes keep one
// ascending-d fmaf chain -> bit-identical hid.
__global__ __launch_bounds__(256) void control1_kernel(
    const float* __restrict__ partial, const float* __restrict__ w1, float* __restrict__ hid) {
  __shared__ float w1s[HID][385];   // 73.9 KB
  __shared__ float ps[N_EMBD];
  const int b = blockIdx.x;
  const int tid = threadIdx.x;
  for (int d = tid; d < N_EMBD; d += 256) {
    float sum = 0.f;
    #pragma unroll
    for (int s = 0; s < 16; ++s) sum += partial[(b * 16 + s) * N_EMBD + d];
    ps[d] = sum * (1.f / TLEN);
  }
  float acc = 0.f;
  #pragma unroll
  for (int half = 0; half < 2; ++half) {
    __syncthreads();                 // guards ps (half 0) and w1s reuse (half 1)
    for (int i = tid; i < HID * 384; i += 256) {
      const int r = i / 384, c = i % 384;
      w1s[r][c] = w1[r * N_EMBD + half * 384 + c];
    }
    __syncthreads();
    if (tid < HID) {
      const float* pr = ps + half * 384;
      #pragma unroll 8
      for (int d2 = 0; d2 < 384; ++d2) acc = fmaf(pr[d2], w1s[tid][d2], acc);
    }
  }
  if (tid < HID) hid[b * HID + tid] = fmaxf(acc, 0.f);
}

// ---------------- control2: ck[b][f] = dot(hid[b], w2[f]) ----------------
__global__ void control2_kernel(const float* __restrict__ hid, const float* __restrict__ w2,
                                float* __restrict__ ck) {
  const int b = blockIdx.y;
  const int f = blockIdx.x * 256 + threadIdx.x;
  __shared__ float hid_s[HID];
  if (threadIdx.x < HID) hid_s[threadIdx.x] = hid[b * HID + threadIdx.x];
  __syncthreads();
  const float* wr = w2 + (size_t)f * HID;
  float acc = 0.f;
  #pragma unroll
  for (int j = 0; j < HID; ++j) acc = fmaf(hid_s[j], wr[j], acc);
  ck[b * FULL + f] = acc;
}

// ---------------- top-K selection (radix select, keys in registers) ----------------
__global__ void topk_kernel(const float* __restrict__ ck, int* __restrict__ sel) {
  const int b = blockIdx.x;
  const int tid = threadIdx.x;               // 256
  const int lane = tid & 63, wv = tid >> 6;
  unsigned key[48];
  const int f_lo = tid * 48;
  #pragma unroll
  for (int i = 0; i < 48; ++i) {
    unsigned u = __float_as_uint(ck[b * FULL + f_lo + i]);
    key[i] = (u & 0x80000000u) ? ~u : (u | 0x80000000u);  // order-preserving map
  }
  __shared__ unsigned redw[4];
  __shared__ int sg[257], se[257];
  unsigned prefix = 0;
  int remaining = KSEL;
  for (int bit = 31; bit >= 0; --bit) {
    const unsigned want = prefix | (1u << bit);
    const unsigned shifted = want >> bit;
    int cnt = 0;
    #pragma unroll
    for (int i = 0; i < 48; ++i) cnt += ((key[i] >> bit) == shifted) ? 1 : 0;
    #pragma unroll
    for (int off = 1; off < 64; off <<= 1) cnt += __shfl_xor(cnt, off, 64);
    if (lane == 0) redw[wv] = (unsigned)cnt;
    __syncthreads();
    const int c = (int)(redw[0] + redw[1] + redw[2] + redw[3]);
    __syncthreads();
    if (c >= remaining) prefix = want;
    else remaining -= c;
  }
  const unsigned kth = prefix;
  int cg = 0, ce = 0;
  #pragma unroll
  for (int i = 0; i < 48; ++i) { cg += (key[i] > kth) ? 1 : 0; ce += (key[i] == kth) ? 1 : 0; }
  sg[tid] = cg; se[tid] = ce;
  __syncthreads();
  if (tid == 0) {
    int ag = 0, ae = 0;
    for (int i = 0; i < 256; ++i) {
      int tg = sg[i], te = se[i];
      sg[i] = ag; se[i] = ae;
      ag += tg; ae += te;
    }
    sg[256] = ag;
  }
  __syncthreads();
  const int ng = sg[256];
  int gpos = sg[tid], epos = se[tid];
  #pragma unroll
  for (int i = 0; i < 48; ++i) {
    const unsigned k = key[i];
    const int f = f_lo + i;
    if (k > kth) {
      sel[b * KSEL + (gpos++)] = f;
    } else if (k == kth) {
      const int p = ng + epos;
      if (p < KSEL) sel[b * KSEL + p] = f;
      ++epos;
    }
  }
}

// ---------------- fp32 -> bf16 round (w_mfc, hi only) ----------------
__global__ void round_w_kernel(const float* __restrict__ src, unsigned short* __restrict__ dst, int n4) {
  const int idx = blockIdx.x * 256 + threadIdx.x;
  if (idx >= n4) return;
  const float4 v = ((const float4*)src)[idx];
  u16x4 h;
  h.x = f2bf(v.x); h.y = f2bf(v.y); h.z = f2bf(v.z); h.w = f2bf(v.w);
  ((u16x4*)dst)[idx] = h;
}

// ---------------- gather w_proj -> wp[b][e][kk] bf16, ONE pass over w_proj ----------------
// One block per e-row: stage row once in LDS (bf16), emit all 8 batches from LDS.
// w_proj read once total (37.7 MB) instead of once per batch.
__global__ __launch_bounds__(256) void gather_wp_kernel(
    const float* __restrict__ wproj, const int* __restrict__ sel,
    unsigned short* __restrict__ wph) {
  __shared__ unsigned short row_s[FULL];   // 24.6 KB
  const int e = blockIdx.x;                // 0..767
  const int tid = threadIdx.x;
  const float* wr = wproj + (size_t)e * FULL;
  #pragma unroll
  for (int i = 0; i < FULL / 4 / 256; ++i) {   // 12 float4 per thread
    const int idx = tid + i * 256;
    const float4 v = ((const float4*)wr)[idx];
    u16x4 h;
    h.x = f2bf(v.x); h.y = f2bf(v.y); h.z = f2bf(v.z); h.w = f2bf(v.w);
    *(u16x4*)(row_s + idx * 4) = h;
  }
  __syncthreads();
  // 8 b x 384 chunks of 8 kk = 3072 chunks; 12 per thread
  #pragma unroll
  for (int i = 0; i < 12; ++i) {
    const int idx = tid + i * 256;
    const int b = idx / 384, c = idx % 384;
    const int* sp = sel + b * KSEL + c * 8;
    const int4 s0 = ((const int4*)sp)[0];
    const int4 s1 = ((const int4*)sp)[1];
    u16x8 v;
    v[0] = row_s[s0.x]; v[1] = row_s[s0.y]; v[2] = row_s[s0.z]; v[3] = row_s[s0.w];
    v[4] = row_s[s1.x]; v[5] = row_s[s1.y]; v[6] = row_s[s1.z]; v[7] = row_s[s1.w];
    *(u16x8*)(wph + ((size_t)(b * N_EMBD + e)) * KSEL + c * 8) = v;
  }
}

// ---------------- GEMM1 (MFMA 2-product, dbuf): h = relu((xh+xl) @ gather(bf16(w_mfc), sel)^T) ----
// 128x128 tile, BK=32, 4 waves (2x2 of 64x64). 48KB LDS (2 x {Axh 8K | Axl 8K | Bwh 8K}).
__global__ __launch_bounds__(256) void gemm1_mfma(
    const unsigned short* __restrict__ xh, const unsigned short* __restrict__ xl,
    const unsigned short* __restrict__ wh, const int* __restrict__ sel,
    unsigned short* __restrict__ hh) {
  __shared__ __align__(16) char sm[49152];
  const int nx = TLEN / 128, ny = KSEL / 128;          // 8, 24
  const int nwg = nx * ny * BATCH;                     // 1536 (divisible by 8)
  int lin = blockIdx.x + nx * (blockIdx.y + ny * blockIdx.z);
  int swz = (lin & 7) * (nwg >> 3) + (lin >> 3);       // XCD-contiguous chunks
  const int bx = swz % nx; int tmp = swz / nx;
  const int by = tmp % ny; const int b = tmp / ny;
  const int t0 = bx * 128, f0 = by * 128;

  const int tid = threadIdx.x;
  const int wv = tid >> 6, lane = tid & 63;
  const int srow = tid >> 2, sslot = tid & 3;
  const int wb = wv * 1024;

  const char* pxh = (const char*)xh;
  const char* pxl = (const char*)xl;
  const char* pwh = (const char*)wh;
  const size_t aoff  = ((size_t)(b * TLEN + t0 + srow)) * 1536 + sslot * 16;  // row stride 768*2B
  const size_t aoff2 = aoff + (size_t)64 * 1536;
  const int* selb = sel + b * KSEL;
  const size_t boff  = (size_t)selb[f0 + srow] * 1536 + sslot * 16;
  const size_t boff2 = (size_t)selb[f0 + srow + 64] * 1536 + sslot * 16;

  const int fr = lane & 15, kg = lane >> 4;
  const int fo = fr * 64 + kg * 16;
  const int m0 = (wv >> 1) * 64, n0 = (wv & 1) * 64;

  f32x4 acc[4][4];
  const f32x4 z4 = {0.f, 0.f, 0.f, 0.f};
  #pragma unroll
  for (int mi = 0; mi < 4; ++mi)
    #pragma unroll
    for (int ni = 0; ni < 4; ++ni) acc[mi][ni] = z4;

  auto stage = [&](int bo, int d) {
    GLDS(pxh + aoff  + d, sm + bo + 0     + wb);
    GLDS(pxh + aoff2 + d, sm + bo + 4096  + wb);
    GLDS(pxl + aoff  + d, sm + bo + 8192  + wb);
    GLDS(pxl + aoff2 + d, sm + bo + 12288 + wb);
    GLDS(pwh + boff  + d, sm + bo + 16384 + wb);
    GLDS(pwh + boff2 + d, sm + bo + 20480 + wb);
  };
  stage(0, 0);
  __syncthreads();
  const int NIT = N_EMBD * 2 / 64;   // 24
  for (int it = 0; it < NIT; ++it) {
    const int cur = (it & 1) ? 24576 : 0;
    if (it + 1 < NIT) stage(cur ^ 24576, (it + 1) * 64);
    bf16x8 ah[4], al[4], bh[4];
    #pragma unroll
    for (int i = 0; i < 4; ++i) {
      const int ra = (m0 + i * 16) * 64 + fo;
      const int rb = (n0 + i * 16) * 64 + fo;
      ah[i] = *(const bf16x8*)(sm + cur + 0     + ra);
      al[i] = *(const bf16x8*)(sm + cur + 8192  + ra);
      bh[i] = *(const bf16x8*)(sm + cur + 16384 + rb);
    }
    #pragma unroll
    for (int mi = 0; mi < 4; ++mi)
      #pragma unroll
      for (int ni = 0; ni < 4; ++ni) {
        acc[mi][ni] = MFMA(ah[mi], bh[ni], acc[mi][ni]);
        acc[mi][ni] = MFMA(al[mi], bh[ni], acc[mi][ni]);
      }
    __syncthreads();
  }
  // epilogue: relu -> bf16, repack through LDS, coalesced 16B stores.
  unsigned short* lh = (unsigned short*)sm;  // [128][128] bf16 = 32KB (fits in 48K)
  const int rowg = lane >> 4, colc = lane & 15;
  #pragma unroll
  for (int mi = 0; mi < 4; ++mi)
    #pragma unroll
    for (int ni = 0; ni < 4; ++ni) {
      const int row = m0 + mi * 16 + rowg * 4;
      const int col = n0 + ni * 16 + colc;
      #pragma unroll
      for (int j = 0; j < 4; ++j)
        lh[(row + j) * 128 + col] = f2bf(fmaxf(acc[mi][ni][j], 0.f));
    }
  __syncthreads();
  const int orow = tid >> 4, oc = tid & 15;
  #pragma unroll
  for (int i2 = 0; i2 < 8; ++i2) {
    const int row = orow + i2 * 16;
    const u16x8 v = *(const u16x8*)&lh[row * 128 + oc * 8];
    *(u16x8*)(hh + ((size_t)(b * TLEN + t0 + row)) * KSEL + f0 + oc * 8) = v;
  }
}

// ---------------- GEMM2 (MFMA 1-product, 128x128 tile, dbuf, b->XCD affinity) ----------------
// out = hh @ wph^T. BK=32, 4 waves (2x2 of 64x64). 32KB LDS (2 x {A 8K | B 8K}).
// Linear grid 384; b = lin & 7 so all 48 blocks of batch b land on XCD b
// (round-robin dispatch) -> wph[b] (4.7 MB) stays L2-resident per XCD.
// Accumulation K-order identical to previous rounds -> bit-identical output.
__global__ __launch_bounds__(256) void gemm2_mfma(
    const unsigned short* __restrict__ hh, const unsigned short* __restrict__ wph,
    float* __restrict__ out) {
  __shared__ __align__(16) char sm[32768];
  const int lin = blockIdx.x;          // 0..383
  const int b = lin & 7;
  const int j = lin >> 3;              // 0..47
  const int bx = j & 7, by = j >> 3;   // bx 0..7 (t-tile), by 0..5 (e-tile)
  const int t0 = bx * 128, e0 = by * 128;

  const int tid = threadIdx.x;
  const int wv = tid >> 6, lane = tid & 63;
  const int wb = wv * 1024;

  const char* pa = (const char*)hh;
  const char* pb = (const char*)wph;
  const size_t aoff  = ((size_t)(b * TLEN + t0 + (tid >> 2))) * 6144 + (tid & 3) * 16;
  const size_t aoff2 = aoff + (size_t)64 * 6144;
  const size_t boff  = ((size_t)(b * N_EMBD + e0 + (tid >> 2))) * 6144 + (tid & 3) * 16;
  const size_t boff2 = boff + (size_t)64 * 6144;

  const int fr = lane & 15, kg = lane >> 4;
  const int fo = fr * 64 + kg * 16;
  const int m0 = (wv >> 1) * 64, n0 = (wv & 1) * 64;

  f32x4 acc[4][4];
  const f32x4 z4 = {0.f, 0.f, 0.f, 0.f};
  #pragma unroll
  for (int mi = 0; mi < 4; ++mi)
    #pragma unroll
    for (int ni = 0; ni < 4; ++ni) acc[mi][ni] = z4;

  auto stage = [&](int bo, int d) {
    GLDS(pa + aoff  + d, sm + bo + 0     + wb);   // A rows 0-63
    GLDS(pa + aoff2 + d, sm + bo + 4096  + wb);   // A rows 64-127
    GLDS(pb + boff  + d, sm + bo + 8192  + wb);   // B rows 0-63
    GLDS(pb + boff2 + d, sm + bo + 12288 + wb);   // B rows 64-127
  };
  stage(0, 0);
  __syncthreads();
  const int NIT = KSEL * 2 / 64;        // 96
  for (int it = 0; it < NIT; ++it) {
    const int cur = (it & 1) ? 16384 : 0;
    if (it + 1 < NIT) stage(cur ^ 16384, (it + 1) * 64);
    bf16x8 ah[4], bh[4];
    #pragma unroll
    for (int i = 0; i < 4; ++i) {
      ah[i] = *(const bf16x8*)(sm + cur + 0    + (m0 + i * 16) * 64 + fo);
      bh[i] = *(const bf16x8*)(sm + cur + 8192 + (n0 + i * 16) * 64 + fo);
    }
    #pragma unroll
    for (int mi = 0; mi < 4; ++mi)
      #pragma unroll
      for (int ni = 0; ni < 4; ++ni)
        acc[mi][ni] = MFMA(ah[mi], bh[ni], acc[mi][ni]);
    __syncthreads();
  }
  const int rowg = lane >> 4, colc = lane & 15;
  #pragma unroll
  for (int mi = 0; mi < 4; ++mi)
    #pragma unroll
    for (int ni = 0; ni < 4; ++ni) {
      const int m = t0 + m0 + mi * 16 + rowg * 4;
      const int e = e0 + n0 + ni * 16 + colc;
      const size_t base = ((size_t)(b * TLEN + m)) * N_EMBD + e;
      #pragma unroll
      for (int jj = 0; jj < 4; ++jj)
        out[base + (size_t)jj * N_EMBD] = acc[mi][ni][jj];
    }
}

// ---------------- launch ----------------
extern "C" void kernel_launch(void* const* d_in, const int* in_sizes, int n_in,
                              void* d_out, int out_size, void* d_ws, size_t ws_size,
                              hipStream_t stream) {
  const float* x      = (const float*)d_in[0];
  const float* w1     = (const float*)d_in[1];
  const float* w2     = (const float*)d_in[2];
  const float* w_mfc  = (const float*)d_in[3];
  const float* w_proj = (const float*)d_in[4];
  float* out = (float*)d_out;

  char* ws = (char*)d_ws;
  size_t off = 0;
  auto alloc = [&](size_t bytes) -> void* {
    void* p = ws + off;
    off += (bytes + 255) & ~(size_t)255;
    return p;
  };
  const size_t NX  = (size_t)BATCH * TLEN * N_EMBD;   // 6,291,456
  const size_t NW  = (size_t)FULL * N_EMBD;           // 9,437,184
  const size_t NWP = (size_t)BATCH * N_EMBD * KSEL;   // 18,874,368
  const size_t NH  = (size_t)BATCH * TLEN * KSEL;     // 25,165,824

  float* partial = (float*)alloc((size_t)BATCH * 16 * N_EMBD * 4);
  float* hid     = (float*)alloc((size_t)BATCH * HID * 4);
  float* ckbuf   = (float*)alloc((size_t)BATCH * FULL * 4);
  int*   sel     = (int*)  alloc((size_t)BATCH * KSEL * 4);
  unsigned short* xh  = (unsigned short*)alloc(NX * 2);
  unsigned short* xl  = (unsigned short*)alloc(NX * 2);
  unsigned short* wh  = (unsigned short*)alloc(NW * 2);
  unsigned short* wph = (unsigned short*)alloc(NWP * 2);
  unsigned short* hh  = (unsigned short*)alloc(NH * 2);

  // x: split + partial pool in one pass over x (per-d t-order identical to prior rounds)
  split_pool_x<<<dim3(16, BATCH, 3), 64, 0, stream>>>(x, xh, xl, partial);
  // w_mfc round to bf16 (independent)
  round_w_kernel<<<(int)(NW / 4 / 256), 256, 0, stream>>>(w_mfc, wh, (int)(NW / 4));
  // control path (exact fp32, FP-order-identical to prior rounds -> same sel)
  control1_kernel<<<BATCH, 256, 0, stream>>>(partial, w1, hid);
  control2_kernel<<<dim3(FULL / 256, BATCH), 256, 0, stream>>>(hid, w2, ckbuf);
  topk_kernel<<<BATCH, 256, 0, stream>>>(ckbuf, sel);
  // per-batch compacted w_proj operand (bf16), single pass over w_proj
  gather_wp_kernel<<<768, 256, 0, stream>>>(w_proj, sel, wph);
  // sparse heavy path on MFMA
  gemm1_mfma<<<dim3(TLEN / 128, KSEL / 128, BATCH), 256, 0, stream>>>(xh, xl, wh, sel, hh);
  gemm2_mfma<<<384, 256, 0, stream>>>(hh, wph, out);
}

// Round 7
// 324.088 us; speedup vs baseline: 3.9854x; 1.1804x over previous
//
#include <hip/hip_runtime.h>

#define N_EMBD 768
#define FULL   12288
#define KSEL   3072
#define BATCH  8
#define TLEN   1024
#define HID    48

typedef short bf16x8 __attribute__((ext_vector_type(8)));
typedef float f32x4 __attribute__((ext_vector_type(4)));
typedef unsigned short u16x4 __attribute__((ext_vector_type(4)));
typedef unsigned short u16x8 __attribute__((ext_vector_type(8)));

#define MFMA(a, b, c) __builtin_amdgcn_mfma_f32_16x16x32_bf16((a), (b), (c), 0, 0, 0)
#define GLDS(g, l) __builtin_amdgcn_global_load_lds( \
    (const __attribute__((address_space(1))) void*)(const void*)(g), \
    (__attribute__((address_space(3))) void*)(void*)(l), 16, 0, 0)

__device__ __forceinline__ unsigned short f2bf(float f) {
  unsigned u = __float_as_uint(f);
  u += 0x7fffu + ((u >> 16) & 1u);   // round-to-nearest-even
  return (unsigned short)(u >> 16);
}
__device__ __forceinline__ float bf2f(unsigned short h) {
  return __uint_as_float(((unsigned)h) << 16);
}

// ---------------- fused: round x -> bf16 + partial pooling ----------------
// Per-d 64-t serial sum order unchanged vs prior rounds -> bit-identical partial.
__global__ void split_pool_x(const float* __restrict__ x, unsigned short* __restrict__ xh,
                             float* __restrict__ partial) {
  const int s = blockIdx.x;   // 0..15 t-chunk of 64
  const int b = blockIdx.y;
  const int d = blockIdx.z * 256 + threadIdx.x * 4;   // z: 0..2, tid: 0..63
  const float* base = x + ((size_t)(b * TLEN + s * 64)) * N_EMBD + d;
  float4 sum = {0.f, 0.f, 0.f, 0.f};
  for (int t = 0; t < 64; ++t) {
    const float4 v = *(const float4*)(base + (size_t)t * N_EMBD);
    sum.x += v.x; sum.y += v.y; sum.z += v.z; sum.w += v.w;
    u16x4 h;
    h.x = f2bf(v.x); h.y = f2bf(v.y); h.z = f2bf(v.z); h.w = f2bf(v.w);
    *(u16x4*)(xh + ((size_t)(b * TLEN + s * 64 + t)) * N_EMBD + d) = h;
  }
  float* pp = partial + (b * 16 + s) * N_EMBD + d;
  pp[0] = sum.x; pp[1] = sum.y; pp[2] = sum.z; pp[3] = sum.w;
}

// ---------------- control1 (fused pool_final): hid[b][i] = relu(dot(pooled[b], w1[i])) ----
__global__ __launch_bounds__(256) void control1_kernel(
    const float* __restrict__ partial, const float* __restrict__ w1, float* __restrict__ hid) {
  __shared__ float w1s[HID][385];   // 73.9 KB
  __shared__ float ps[N_EMBD];
  const int b = blockIdx.x;
  const int tid = threadIdx.x;
  for (int d = tid; d < N_EMBD; d += 256) {
    float sum = 0.f;
    #pragma unroll
    for (int s = 0; s < 16; ++s) sum += partial[(b * 16 + s) * N_EMBD + d];
    ps[d] = sum * (1.f / TLEN);
  }
  float acc = 0.f;
  #pragma unroll
  for (int half = 0; half < 2; ++half) {
    __syncthreads();                 // guards ps (half 0) and w1s reuse (half 1)
    for (int i = tid; i < HID * 384; i += 256) {
      const int r = i / 384, c = i % 384;
      w1s[r][c] = w1[r * N_EMBD + half * 384 + c];
    }
    __syncthreads();
    if (tid < HID) {
      const float* pr = ps + half * 384;
      #pragma unroll 8
      for (int d2 = 0; d2 < 384; ++d2) acc = fmaf(pr[d2], w1s[tid][d2], acc);
    }
  }
  if (tid < HID) hid[b * HID + tid] = fmaxf(acc, 0.f);
}

// ---------------- control2: ck[b][f] = dot(hid[b], w2[f]) ----------------
__global__ void control2_kernel(const float* __restrict__ hid, const float* __restrict__ w2,
                                float* __restrict__ ck) {
  const int b = blockIdx.y;
  const int f = blockIdx.x * 256 + threadIdx.x;
  __shared__ float hid_s[HID];
  if (threadIdx.x < HID) hid_s[threadIdx.x] = hid[b * HID + threadIdx.x];
  __syncthreads();
  const float* wr = w2 + (size_t)f * HID;
  float acc = 0.f;
  #pragma unroll
  for (int j = 0; j < HID; ++j) acc = fmaf(hid_s[j], wr[j], acc);
  ck[b * FULL + f] = acc;
}

// ---------------- top-K selection (radix select, keys in registers) ----------------
__global__ void topk_kernel(const float* __restrict__ ck, int* __restrict__ sel) {
  const int b = blockIdx.x;
  const int tid = threadIdx.x;               // 256
  const int lane = tid & 63, wv = tid >> 6;
  unsigned key[48];
  const int f_lo = tid * 48;
  #pragma unroll
  for (int i = 0; i < 48; ++i) {
    unsigned u = __float_as_uint(ck[b * FULL + f_lo + i]);
    key[i] = (u & 0x80000000u) ? ~u : (u | 0x80000000u);  // order-preserving map
  }
  __shared__ unsigned redw[4];
  __shared__ int sg[257], se[257];
  unsigned prefix = 0;
  int remaining = KSEL;
  for (int bit = 31; bit >= 0; --bit) {
    const unsigned want = prefix | (1u << bit);
    const unsigned shifted = want >> bit;
    int cnt = 0;
    #pragma unroll
    for (int i = 0; i < 48; ++i) cnt += ((key[i] >> bit) == shifted) ? 1 : 0;
    #pragma unroll
    for (int off = 1; off < 64; off <<= 1) cnt += __shfl_xor(cnt, off, 64);
    if (lane == 0) redw[wv] = (unsigned)cnt;
    __syncthreads();
    const int c = (int)(redw[0] + redw[1] + redw[2] + redw[3]);
    __syncthreads();
    if (c >= remaining) prefix = want;
    else remaining -= c;
  }
  const unsigned kth = prefix;
  int cg = 0, ce = 0;
  #pragma unroll
  for (int i = 0; i < 48; ++i) { cg += (key[i] > kth) ? 1 : 0; ce += (key[i] == kth) ? 1 : 0; }
  sg[tid] = cg; se[tid] = ce;
  __syncthreads();
  if (tid == 0) {
    int ag = 0, ae = 0;
    for (int i = 0; i < 256; ++i) {
      int tg = sg[i], te = se[i];
      sg[i] = ag; se[i] = ae;
      ag += tg; ae += te;
    }
    sg[256] = ag;
  }
  __syncthreads();
  const int ng = sg[256];
  int gpos = sg[tid], epos = se[tid];
  #pragma unroll
  for (int i = 0; i < 48; ++i) {
    const unsigned k = key[i];
    const int f = f_lo + i;
    if (k > kth) {
      sel[b * KSEL + (gpos++)] = f;
    } else if (k == kth) {
      const int p = ng + epos;
      if (p < KSEL) sel[b * KSEL + p] = f;
      ++epos;
    }
  }
}

// ---------------- fp32 -> bf16 round (w_mfc) ----------------
__global__ void round_w_kernel(const float* __restrict__ src, unsigned short* __restrict__ dst, int n4) {
  const int idx = blockIdx.x * 256 + threadIdx.x;
  if (idx >= n4) return;
  const float4 v = ((const float4*)src)[idx];
  u16x4 h;
  h.x = f2bf(v.x); h.y = f2bf(v.y); h.z = f2bf(v.z); h.w = f2bf(v.w);
  ((u16x4*)dst)[idx] = h;
}

// ---------------- gather w_proj -> wp[b][e][kk] bf16, ONE pass over w_proj ----------------
__global__ __launch_bounds__(256) void gather_wp_kernel(
    const float* __restrict__ wproj, const int* __restrict__ sel,
    unsigned short* __restrict__ wph) {
  __shared__ unsigned short row_s[FULL];   // 24.6 KB
  const int e = blockIdx.x;                // 0..767
  const int tid = threadIdx.x;
  const float* wr = wproj + (size_t)e * FULL;
  #pragma unroll
  for (int i = 0; i < FULL / 4 / 256; ++i) {   // 12 float4 per thread
    const int idx = tid + i * 256;
    const float4 v = ((const float4*)wr)[idx];
    u16x4 h;
    h.x = f2bf(v.x); h.y = f2bf(v.y); h.z = f2bf(v.z); h.w = f2bf(v.w);
    *(u16x4*)(row_s + idx * 4) = h;
  }
  __syncthreads();
  #pragma unroll
  for (int i = 0; i < 12; ++i) {
    const int idx = tid + i * 256;
    const int b = idx / 384, c = idx % 384;
    const int* sp = sel + b * KSEL + c * 8;
    const int4 s0 = ((const int4*)sp)[0];
    const int4 s1 = ((const int4*)sp)[1];
    u16x8 v;
    v[0] = row_s[s0.x]; v[1] = row_s[s0.y]; v[2] = row_s[s0.z]; v[3] = row_s[s0.w];
    v[4] = row_s[s1.x]; v[5] = row_s[s1.y]; v[6] = row_s[s1.z]; v[7] = row_s[s1.w];
    *(u16x8*)(wph + ((size_t)(b * N_EMBD + e)) * KSEL + c * 8) = v;
  }
}

// ---------------- GEMM1 (MFMA 1-product bf16, dbuf): h = relu(xh @ gather(wh, sel)^T) ----
// 128x128 tile, BK=32, 4 waves (2x2 of 64x64). 32KB LDS (2 x {A 8K | B 8K}).
__global__ __launch_bounds__(256) void gemm1_mfma(
    const unsigned short* __restrict__ xh, const unsigned short* __restrict__ wh,
    const int* __restrict__ sel, unsigned short* __restrict__ hh) {
  __shared__ __align__(16) char sm[32768];
  const int nx = TLEN / 128, ny = KSEL / 128;          // 8, 24
  const int nwg = nx * ny * BATCH;                     // 1536 (divisible by 8)
  int lin = blockIdx.x + nx * (blockIdx.y + ny * blockIdx.z);
  int swz = (lin & 7) * (nwg >> 3) + (lin >> 3);       // XCD-contiguous chunks
  const int bx = swz % nx; int tmp = swz / nx;
  const int by = tmp % ny; const int b = tmp / ny;
  const int t0 = bx * 128, f0 = by * 128;

  const int tid = threadIdx.x;
  const int wv = tid >> 6, lane = tid & 63;
  const int srow = tid >> 2, sslot = tid & 3;
  const int wb = wv * 1024;

  const char* pxh = (const char*)xh;
  const char* pwh = (const char*)wh;
  const size_t aoff  = ((size_t)(b * TLEN + t0 + srow)) * 1536 + sslot * 16;  // row stride 768*2B
  const size_t aoff2 = aoff + (size_t)64 * 1536;
  const int* selb = sel + b * KSEL;
  const size_t boff  = (size_t)selb[f0 + srow] * 1536 + sslot * 16;
  const size_t boff2 = (size_t)selb[f0 + srow + 64] * 1536 + sslot * 16;

  const int fr = lane & 15, kg = lane >> 4;
  const int fo = fr * 64 + kg * 16;
  const int m0 = (wv >> 1) * 64, n0 = (wv & 1) * 64;

  f32x4 acc[4][4];
  const f32x4 z4 = {0.f, 0.f, 0.f, 0.f};
  #pragma unroll
  for (int mi = 0; mi < 4; ++mi)
    #pragma unroll
    for (int ni = 0; ni < 4; ++ni) acc[mi][ni] = z4;

  auto stage = [&](int bo, int d) {
    GLDS(pxh + aoff  + d, sm + bo + 0     + wb);
    GLDS(pxh + aoff2 + d, sm + bo + 4096  + wb);
    GLDS(pwh + boff  + d, sm + bo + 8192  + wb);
    GLDS(pwh + boff2 + d, sm + bo + 12288 + wb);
  };
  stage(0, 0);
  __syncthreads();
  const int NIT = N_EMBD * 2 / 64;   // 24
  for (int it = 0; it < NIT; ++it) {
    const int cur = (it & 1) ? 16384 : 0;
    if (it + 1 < NIT) stage(cur ^ 16384, (it + 1) * 64);
    bf16x8 ah[4], bh[4];
    #pragma unroll
    for (int i = 0; i < 4; ++i) {
      ah[i] = *(const bf16x8*)(sm + cur + 0    + (m0 + i * 16) * 64 + fo);
      bh[i] = *(const bf16x8*)(sm + cur + 8192 + (n0 + i * 16) * 64 + fo);
    }
    #pragma unroll
    for (int mi = 0; mi < 4; ++mi)
      #pragma unroll
      for (int ni = 0; ni < 4; ++ni)
        acc[mi][ni] = MFMA(ah[mi], bh[ni], acc[mi][ni]);
    __syncthreads();
  }
  // epilogue: relu -> bf16, repack through LDS, coalesced 16B stores.
  unsigned short* lh = (unsigned short*)sm;  // [128][128] bf16 = 32KB
  const int rowg = lane >> 4, colc = lane & 15;
  #pragma unroll
  for (int mi = 0; mi < 4; ++mi)
    #pragma unroll
    for (int ni = 0; ni < 4; ++ni) {
      const int row = m0 + mi * 16 + rowg * 4;
      const int col = n0 + ni * 16 + colc;
      #pragma unroll
      for (int j = 0; j < 4; ++j)
        lh[(row + j) * 128 + col] = f2bf(fmaxf(acc[mi][ni][j], 0.f));
    }
  __syncthreads();
  const int orow = tid >> 4, oc = tid & 15;
  #pragma unroll
  for (int i2 = 0; i2 < 8; ++i2) {
    const int row = orow + i2 * 16;
    const u16x8 v = *(const u16x8*)&lh[row * 128 + oc * 8];
    *(u16x8*)(hh + ((size_t)(b * TLEN + t0 + row)) * KSEL + f0 + oc * 8) = v;
  }
}

// ---------------- GEMM2 (MFMA 1-product, BK=64 dual-chunk, dbuf, b->XCD affinity) ----------------
// out = hh @ wph^T. 128x64 tile, 4 waves (2x2 of 64x32), 768 blocks (3/CU).
// b = lin&7: round-robin dispatch puts all of batch b's 96 blocks on one XCD
// -> wph[b] (4.7MB) mostly L2-resident. 48KB LDS (2 x {A0 8K|A1 8K|B0 4K|B1 4K}).
__global__ __launch_bounds__(256) void gemm2_mfma(
    const unsigned short* __restrict__ hh, const unsigned short* __restrict__ wph,
    float* __restrict__ out) {
  __shared__ __align__(16) char sm[49152];
  const int lin = blockIdx.x;          // 0..767
  const int b = lin & 7;
  const int j = lin >> 3;              // 0..95
  const int bx = j & 7, by = j >> 3;   // bx 0..7 (t-tile), by 0..11 (e-tile)
  const int t0 = bx * 128, e0 = by * 64;

  const int tid = threadIdx.x;
  const int wv = tid >> 6, lane = tid & 63;
  const int wb = wv * 1024;

  const char* pa = (const char*)hh;
  const char* pb = (const char*)wph;
  const size_t aoff  = ((size_t)(b * TLEN + t0 + (tid >> 2))) * 6144 + (tid & 3) * 16;
  const size_t aoff2 = aoff + (size_t)64 * 6144;
  const size_t boff  = ((size_t)(b * N_EMBD + e0 + (tid >> 2))) * 6144 + (tid & 3) * 16;

  const int fr = lane & 15, kg = lane >> 4;
  const int fo = fr * 64 + kg * 16;
  const int m0 = (wv >> 1) * 64, n0 = (wv & 1) * 32;

  f32x4 acc[4][2];
  const f32x4 z4 = {0.f, 0.f, 0.f, 0.f};
  #pragma unroll
  for (int mi = 0; mi < 4; ++mi)
    #pragma unroll
    for (int ni = 0; ni < 2; ++ni) acc[mi][ni] = z4;

  auto stage = [&](int bo, int d) {
    GLDS(pa + aoff  + d,      sm + bo + 0     + wb);   // A rows 0-63,  k-chunk 0
    GLDS(pa + aoff2 + d,      sm + bo + 4096  + wb);   // A rows 64-127, chunk 0
    GLDS(pa + aoff  + d + 64, sm + bo + 8192  + wb);   // A rows 0-63,  chunk 1
    GLDS(pa + aoff2 + d + 64, sm + bo + 12288 + wb);   // A rows 64-127, chunk 1
    GLDS(pb + boff  + d,      sm + bo + 16384 + wb);   // B chunk 0
    GLDS(pb + boff  + d + 64, sm + bo + 20480 + wb);   // B chunk 1
  };
  stage(0, 0);
  __syncthreads();
  const int NIT = KSEL * 2 / 128;        // 48
  for (int it = 0; it < NIT; ++it) {
    const int cur = (it & 1) ? 24576 : 0;
    if (it + 1 < NIT) stage(cur ^ 24576, (it + 1) * 128);
    bf16x8 ah[4][2], bh[2][2];
    #pragma unroll
    for (int i = 0; i < 4; ++i) {
      const int ra = (m0 + i * 16) * 64 + fo;
      ah[i][0] = *(const bf16x8*)(sm + cur + 0    + ra);
      ah[i][1] = *(const bf16x8*)(sm + cur + 8192 + ra);
    }
    #pragma unroll
    for (int i = 0; i < 2; ++i) {
      const int rb = (n0 + i * 16) * 64 + fo;
      bh[i][0] = *(const bf16x8*)(sm + cur + 16384 + rb);
      bh[i][1] = *(const bf16x8*)(sm + cur + 20480 + rb);
    }
    #pragma unroll
    for (int c = 0; c < 2; ++c)
      #pragma unroll
      for (int mi = 0; mi < 4; ++mi)
        #pragma unroll
        for (int ni = 0; ni < 2; ++ni)
          acc[mi][ni] = MFMA(ah[mi][c], bh[ni][c], acc[mi][ni]);
    __syncthreads();
  }
  const int rowg = lane >> 4, colc = lane & 15;
  #pragma unroll
  for (int mi = 0; mi < 4; ++mi)
    #pragma unroll
    for (int ni = 0; ni < 2; ++ni) {
      const int m = t0 + m0 + mi * 16 + rowg * 4;
      const int e = e0 + n0 + ni * 16 + colc;
      const size_t base = ((size_t)(b * TLEN + m)) * N_EMBD + e;
      #pragma unroll
      for (int jj = 0; jj < 4; ++jj)
        out[base + (size_t)jj * N_EMBD] = acc[mi][ni][jj];
    }
}

// ---------------- launch ----------------
extern "C" void kernel_launch(void* const* d_in, const int* in_sizes, int n_in,
                              void* d_out, int out_size, void* d_ws, size_t ws_size,
                              hipStream_t stream) {
  const float* x      = (const float*)d_in[0];
  const float* w1     = (const float*)d_in[1];
  const float* w2     = (const float*)d_in[2];
  const float* w_mfc  = (const float*)d_in[3];
  const float* w_proj = (const float*)d_in[4];
  float* out = (float*)d_out;

  char* ws = (char*)d_ws;
  size_t off = 0;
  auto alloc = [&](size_t bytes) -> void* {
    void* p = ws + off;
    off += (bytes + 255) & ~(size_t)255;
    return p;
  };
  const size_t NX  = (size_t)BATCH * TLEN * N_EMBD;   // 6,291,456
  const size_t NW  = (size_t)FULL * N_EMBD;           // 9,437,184
  const size_t NWP = (size_t)BATCH * N_EMBD * KSEL;   // 18,874,368
  const size_t NH  = (size_t)BATCH * TLEN * KSEL;     // 25,165,824

  float* partial = (float*)alloc((size_t)BATCH * 16 * N_EMBD * 4);
  float* hid     = (float*)alloc((size_t)BATCH * HID * 4);
  float* ckbuf   = (float*)alloc((size_t)BATCH * FULL * 4);
  int*   sel     = (int*)  alloc((size_t)BATCH * KSEL * 4);
  unsigned short* xh  = (unsigned short*)alloc(NX * 2);
  unsigned short* wh  = (unsigned short*)alloc(NW * 2);
  unsigned short* wph = (unsigned short*)alloc(NWP * 2);
  unsigned short* hh  = (unsigned short*)alloc(NH * 2);

  // x: round to bf16 + partial pool in one pass (per-d t-order identical to prior rounds)
  split_pool_x<<<dim3(16, BATCH, 3), 64, 0, stream>>>(x, xh, partial);
  // w_mfc round to bf16 (independent)
  round_w_kernel<<<(int)(NW / 4 / 256), 256, 0, stream>>>(w_mfc, wh, (int)(NW / 4));
  // control path (exact fp32, FP-order-identical to prior rounds -> same sel)
  control1_kernel<<<BATCH, 256, 0, stream>>>(partial, w1, hid);
  control2_kernel<<<dim3(FULL / 256, BATCH), 256, 0, stream>>>(hid, w2, ckbuf);
  topk_kernel<<<BATCH, 256, 0, stream>>>(ckbuf, sel);
  // per-batch compacted w_proj operand (bf16), single pass over w_proj
  gather_wp_kernel<<<768, 256, 0, stream>>>(w_proj, sel, wph);
  // sparse heavy path on MFMA
  gemm1_mfma<<<dim3(TLEN / 128, KSEL / 128, BATCH), 256, 0, stream>>>(xh, wh, sel, hh);
  gemm2_mfma<<<768, 256, 0, stream>>>(hh, wph, out);
}

// Round 8
// 323.430 us; speedup vs baseline: 3.9935x; 1.0020x over previous
//
#include <hip/hip_runtime.h>

#define N_EMBD 768
#define FULL   12288
#define KSEL   3072
#define BATCH  8
#define TLEN   1024
#define HID    48

typedef short bf16x8 __attribute__((ext_vector_type(8)));
typedef float f32x4 __attribute__((ext_vector_type(4)));
typedef unsigned short u16x4 __attribute__((ext_vector_type(4)));
typedef unsigned short u16x8 __attribute__((ext_vector_type(8)));

#define MFMA(a, b, c) __builtin_amdgcn_mfma_f32_16x16x32_bf16((a), (b), (c), 0, 0, 0)
#define GLDS(g, l) __builtin_amdgcn_global_load_lds( \
    (const __attribute__((address_space(1))) void*)(const void*)(g), \
    (__attribute__((address_space(3))) void*)(void*)(l), 16, 0, 0)

__device__ __forceinline__ unsigned short f2bf(float f) {
  unsigned u = __float_as_uint(f);
  u += 0x7fffu + ((u >> 16) & 1u);   // round-to-nearest-even
  return (unsigned short)(u >> 16);
}
__device__ __forceinline__ float bf2f(unsigned short h) {
  return __uint_as_float(((unsigned)h) << 16);
}

// ---------------- fused: round x -> bf16 + partial pooling ----------------
// Per-d 64-t serial sum order unchanged vs prior rounds -> bit-identical partial.
__global__ void split_pool_x(const float* __restrict__ x, unsigned short* __restrict__ xh,
                             float* __restrict__ partial) {
  const int s = blockIdx.x;   // 0..15 t-chunk of 64
  const int b = blockIdx.y;
  const int d = blockIdx.z * 256 + threadIdx.x * 4;   // z: 0..2, tid: 0..63
  const float* base = x + ((size_t)(b * TLEN + s * 64)) * N_EMBD + d;
  float4 sum = {0.f, 0.f, 0.f, 0.f};
  for (int t = 0; t < 64; ++t) {
    const float4 v = *(const float4*)(base + (size_t)t * N_EMBD);
    sum.x += v.x; sum.y += v.y; sum.z += v.z; sum.w += v.w;
    u16x4 h;
    h.x = f2bf(v.x); h.y = f2bf(v.y); h.z = f2bf(v.z); h.w = f2bf(v.w);
    *(u16x4*)(xh + ((size_t)(b * TLEN + s * 64 + t)) * N_EMBD + d) = h;
  }
  float* pp = partial + (b * 16 + s) * N_EMBD + d;
  pp[0] = sum.x; pp[1] = sum.y; pp[2] = sum.z; pp[3] = sum.w;
}

// ---------------- control1 (fused pool_final): hid[b][i] = relu(dot(pooled[b], w1[i])) ----
__global__ __launch_bounds__(256) void control1_kernel(
    const float* __restrict__ partial, const float* __restrict__ w1, float* __restrict__ hid) {
  __shared__ float w1s[HID][385];   // 73.9 KB
  __shared__ float ps[N_EMBD];
  const int b = blockIdx.x;
  const int tid = threadIdx.x;
  for (int d = tid; d < N_EMBD; d += 256) {
    float sum = 0.f;
    #pragma unroll
    for (int s = 0; s < 16; ++s) sum += partial[(b * 16 + s) * N_EMBD + d];
    ps[d] = sum * (1.f / TLEN);
  }
  float acc = 0.f;
  #pragma unroll
  for (int half = 0; half < 2; ++half) {
    __syncthreads();                 // guards ps (half 0) and w1s reuse (half 1)
    for (int i = tid; i < HID * 384; i += 256) {
      const int r = i / 384, c = i % 384;
      w1s[r][c] = w1[r * N_EMBD + half * 384 + c];
    }
    __syncthreads();
    if (tid < HID) {
      const float* pr = ps + half * 384;
      #pragma unroll 8
      for (int d2 = 0; d2 < 384; ++d2) acc = fmaf(pr[d2], w1s[tid][d2], acc);
    }
  }
  if (tid < HID) hid[b * HID + tid] = fmaxf(acc, 0.f);
}

// ---------------- control2: ck[b][f] = dot(hid[b], w2[f]) ----------------
__global__ void control2_kernel(const float* __restrict__ hid, const float* __restrict__ w2,
                                float* __restrict__ ck) {
  const int b = blockIdx.y;
  const int f = blockIdx.x * 256 + threadIdx.x;
  __shared__ float hid_s[HID];
  if (threadIdx.x < HID) hid_s[threadIdx.x] = hid[b * HID + threadIdx.x];
  __syncthreads();
  const float* wr = w2 + (size_t)f * HID;
  float acc = 0.f;
  #pragma unroll
  for (int j = 0; j < HID; ++j) acc = fmaf(hid_s[j], wr[j], acc);
  ck[b * FULL + f] = acc;
}

// ---------------- top-K selection (radix select, keys in registers) ----------------
__global__ void topk_kernel(const float* __restrict__ ck, int* __restrict__ sel) {
  const int b = blockIdx.x;
  const int tid = threadIdx.x;               // 256
  const int lane = tid & 63, wv = tid >> 6;
  unsigned key[48];
  const int f_lo = tid * 48;
  #pragma unroll
  for (int i = 0; i < 48; ++i) {
    unsigned u = __float_as_uint(ck[b * FULL + f_lo + i]);
    key[i] = (u & 0x80000000u) ? ~u : (u | 0x80000000u);  // order-preserving map
  }
  __shared__ unsigned redw[4];
  __shared__ int sg[257], se[257];
  unsigned prefix = 0;
  int remaining = KSEL;
  for (int bit = 31; bit >= 0; --bit) {
    const unsigned want = prefix | (1u << bit);
    const unsigned shifted = want >> bit;
    int cnt = 0;
    #pragma unroll
    for (int i = 0; i < 48; ++i) cnt += ((key[i] >> bit) == shifted) ? 1 : 0;
    #pragma unroll
    for (int off = 1; off < 64; off <<= 1) cnt += __shfl_xor(cnt, off, 64);
    if (lane == 0) redw[wv] = (unsigned)cnt;
    __syncthreads();
    const int c = (int)(redw[0] + redw[1] + redw[2] + redw[3]);
    __syncthreads();
    if (c >= remaining) prefix = want;
    else remaining -= c;
  }
  const unsigned kth = prefix;
  int cg = 0, ce = 0;
  #pragma unroll
  for (int i = 0; i < 48; ++i) { cg += (key[i] > kth) ? 1 : 0; ce += (key[i] == kth) ? 1 : 0; }
  sg[tid] = cg; se[tid] = ce;
  __syncthreads();
  if (tid == 0) {
    int ag = 0, ae = 0;
    for (int i = 0; i < 256; ++i) {
      int tg = sg[i], te = se[i];
      sg[i] = ag; se[i] = ae;
      ag += tg; ae += te;
    }
    sg[256] = ag;
  }
  __syncthreads();
  const int ng = sg[256];
  int gpos = sg[tid], epos = se[tid];
  #pragma unroll
  for (int i = 0; i < 48; ++i) {
    const unsigned k = key[i];
    const int f = f_lo + i;
    if (k > kth) {
      sel[b * KSEL + (gpos++)] = f;
    } else if (k == kth) {
      const int p = ng + epos;
      if (p < KSEL) sel[b * KSEL + p] = f;
      ++epos;
    }
  }
}

// ---------------- fp32 -> bf16 round (w_mfc) ----------------
__global__ void round_w_kernel(const float* __restrict__ src, unsigned short* __restrict__ dst, int n4) {
  const int idx = blockIdx.x * 256 + threadIdx.x;
  if (idx >= n4) return;
  const float4 v = ((const float4*)src)[idx];
  u16x4 h;
  h.x = f2bf(v.x); h.y = f2bf(v.y); h.z = f2bf(v.z); h.w = f2bf(v.w);
  ((u16x4*)dst)[idx] = h;
}

// ---------------- gather w_proj -> wp[b][e][kk] bf16, ONE pass over w_proj ----------------
__global__ __launch_bounds__(256) void gather_wp_kernel(
    const float* __restrict__ wproj, const int* __restrict__ sel,
    unsigned short* __restrict__ wph) {
  __shared__ unsigned short row_s[FULL];   // 24.6 KB
  const int e = blockIdx.x;                // 0..767
  const int tid = threadIdx.x;
  const float* wr = wproj + (size_t)e * FULL;
  #pragma unroll
  for (int i = 0; i < FULL / 4 / 256; ++i) {   // 12 float4 per thread
    const int idx = tid + i * 256;
    const float4 v = ((const float4*)wr)[idx];
    u16x4 h;
    h.x = f2bf(v.x); h.y = f2bf(v.y); h.z = f2bf(v.z); h.w = f2bf(v.w);
    *(u16x4*)(row_s + idx * 4) = h;
  }
  __syncthreads();
  #pragma unroll
  for (int i = 0; i < 12; ++i) {
    const int idx = tid + i * 256;
    const int b = idx / 384, c = idx % 384;
    const int* sp = sel + b * KSEL + c * 8;
    const int4 s0 = ((const int4*)sp)[0];
    const int4 s1 = ((const int4*)sp)[1];
    u16x8 v;
    v[0] = row_s[s0.x]; v[1] = row_s[s0.y]; v[2] = row_s[s0.z]; v[3] = row_s[s0.w];
    v[4] = row_s[s1.x]; v[5] = row_s[s1.y]; v[6] = row_s[s1.z]; v[7] = row_s[s1.w];
    *(u16x8*)(wph + ((size_t)(b * N_EMBD + e)) * KSEL + c * 8) = v;
  }
}

// ---------------- GEMM1 (1-product bf16, 3-buffer counted-vmcnt pipeline) ----------------
// h = relu(xh @ gather(wh, sel)^T). 128x128 tile, BK=32, 4 waves (2x2 of 64x64).
// 48KB LDS = 3 x {A 8K | B 8K}; depth-2 prefetch; s_waitcnt vmcnt(4) steady (never 0
// in-loop except final iter). One raw s_barrier per iter. K accumulation order
// identical to round 7 -> bit-identical output.
__global__ __launch_bounds__(256) void gemm1_mfma(
    const unsigned short* __restrict__ xh, const unsigned short* __restrict__ wh,
    const int* __restrict__ sel, unsigned short* __restrict__ hh) {
  __shared__ __align__(16) char sm[49152];
  const int nx = TLEN / 128, ny = KSEL / 128;          // 8, 24
  const int nwg = nx * ny * BATCH;                     // 1536 (divisible by 8)
  int lin = blockIdx.x + nx * (blockIdx.y + ny * blockIdx.z);
  int swz = (lin & 7) * (nwg >> 3) + (lin >> 3);       // XCD-contiguous chunks
  const int bx = swz % nx; int tmp = swz / nx;
  const int by = tmp % ny; const int b = tmp / ny;
  const int t0 = bx * 128, f0 = by * 128;

  const int tid = threadIdx.x;
  const int wv = tid >> 6, lane = tid & 63;
  const int srow = tid >> 2, sslot = tid & 3;
  const int wb = wv * 1024;

  const char* pxh = (const char*)xh;
  const char* pwh = (const char*)wh;
  const size_t aoff  = ((size_t)(b * TLEN + t0 + srow)) * 1536 + sslot * 16;  // row stride 768*2B
  const size_t aoff2 = aoff + (size_t)64 * 1536;
  const int* selb = sel + b * KSEL;
  const size_t boff  = (size_t)selb[f0 + srow] * 1536 + sslot * 16;
  const size_t boff2 = (size_t)selb[f0 + srow + 64] * 1536 + sslot * 16;

  const int fr = lane & 15, kg = lane >> 4;
  const int fo = fr * 64 + kg * 16;
  const int m0 = (wv >> 1) * 64, n0 = (wv & 1) * 64;

  f32x4 acc[4][4];
  const f32x4 z4 = {0.f, 0.f, 0.f, 0.f};
  #pragma unroll
  for (int mi = 0; mi < 4; ++mi)
    #pragma unroll
    for (int ni = 0; ni < 4; ++ni) acc[mi][ni] = z4;

  auto stage = [&](int bo, int kb) {   // kb = K-chunk byte offset (64B per BK=32)
    GLDS(pxh + aoff  + kb, sm + bo + 0     + wb);
    GLDS(pxh + aoff2 + kb, sm + bo + 4096  + wb);
    GLDS(pwh + boff  + kb, sm + bo + 8192  + wb);
    GLDS(pwh + boff2 + kb, sm + bo + 12288 + wb);
  };
  const int NIT = N_EMBD * 2 / 64;   // 24
  stage(0, 0);
  stage(16384, 64);                  // 8 loads in flight
  for (int it = 0; it < NIT; ++it) {
    if (it < NIT - 1) asm volatile("s_waitcnt vmcnt(4)" ::: "memory");
    else              asm volatile("s_waitcnt vmcnt(0)" ::: "memory");
    __builtin_amdgcn_s_barrier();          // buf cur complete for all waves
    __builtin_amdgcn_sched_barrier(0);
    const int cur = (it % 3) << 14;
    if (it + 2 < NIT) stage(((it + 2) % 3) << 14, (it + 2) * 64);
    bf16x8 ah[4], bh[4];
    #pragma unroll
    for (int i = 0; i < 4; ++i) {
      ah[i] = *(const bf16x8*)(sm + cur + 0    + (m0 + i * 16) * 64 + fo);
      bh[i] = *(const bf16x8*)(sm + cur + 8192 + (n0 + i * 16) * 64 + fo);
    }
    #pragma unroll
    for (int mi = 0; mi < 4; ++mi)
      #pragma unroll
      for (int ni = 0; ni < 4; ++ni)
        acc[mi][ni] = MFMA(ah[mi], bh[ni], acc[mi][ni]);
  }
  __syncthreads();   // all reads retired before sm reuse below
  // epilogue: relu -> bf16, repack through LDS, coalesced 16B stores.
  unsigned short* lh = (unsigned short*)sm;  // [128][128] bf16 = 32KB
  const int rowg = lane >> 4, colc = lane & 15;
  #pragma unroll
  for (int mi = 0; mi < 4; ++mi)
    #pragma unroll
    for (int ni = 0; ni < 4; ++ni) {
      const int row = m0 + mi * 16 + rowg * 4;
      const int col = n0 + ni * 16 + colc;
      #pragma unroll
      for (int j = 0; j < 4; ++j)
        lh[(row + j) * 128 + col] = f2bf(fmaxf(acc[mi][ni][j], 0.f));
    }
  __syncthreads();
  const int orow = tid >> 4, oc = tid & 15;
  #pragma unroll
  for (int i2 = 0; i2 < 8; ++i2) {
    const int row = orow + i2 * 16;
    const u16x8 v = *(const u16x8*)&lh[row * 128 + oc * 8];
    *(u16x8*)(hh + ((size_t)(b * TLEN + t0 + row)) * KSEL + f0 + oc * 8) = v;
  }
}

// ---------------- GEMM2 (1-product, BK=64, 3-buffer counted-vmcnt, b->XCD affinity) --------
// out = hh @ wph^T. 128x64 tile, 4 waves (2x2 of 64x32), 768 blocks.
// 72KB LDS = 3 x {A0 8K|A1 8K|B0 4K|B1 4K}; s_waitcnt vmcnt(6) steady.
__global__ __launch_bounds__(256) void gemm2_mfma(
    const unsigned short* __restrict__ hh, const unsigned short* __restrict__ wph,
    float* __restrict__ out) {
  __shared__ __align__(16) char sm[73728];
  const int lin = blockIdx.x;          // 0..767
  const int b = lin & 7;
  const int j = lin >> 3;              // 0..95
  const int bx = j & 7, by = j >> 3;   // bx 0..7 (t-tile), by 0..11 (e-tile)
  const int t0 = bx * 128, e0 = by * 64;

  const int tid = threadIdx.x;
  const int wv = tid >> 6, lane = tid & 63;
  const int wb = wv * 1024;

  const char* pa = (const char*)hh;
  const char* pb = (const char*)wph;
  const size_t aoff  = ((size_t)(b * TLEN + t0 + (tid >> 2))) * 6144 + (tid & 3) * 16;
  const size_t aoff2 = aoff + (size_t)64 * 6144;
  const size_t boff  = ((size_t)(b * N_EMBD + e0 + (tid >> 2))) * 6144 + (tid & 3) * 16;

  const int fr = lane & 15, kg = lane >> 4;
  const int fo = fr * 64 + kg * 16;
  const int m0 = (wv >> 1) * 64, n0 = (wv & 1) * 32;

  f32x4 acc[4][2];
  const f32x4 z4 = {0.f, 0.f, 0.f, 0.f};
  #pragma unroll
  for (int mi = 0; mi < 4; ++mi)
    #pragma unroll
    for (int ni = 0; ni < 2; ++ni) acc[mi][ni] = z4;

  auto stage = [&](int bo, int d) {    // d = K-chunk byte offset (128B per BK=64)
    GLDS(pa + aoff  + d,      sm + bo + 0     + wb);   // A rows 0-63,  k-chunk 0
    GLDS(pa + aoff2 + d,      sm + bo + 4096  + wb);   // A rows 64-127, chunk 0
    GLDS(pa + aoff  + d + 64, sm + bo + 8192  + wb);   // A rows 0-63,  chunk 1
    GLDS(pa + aoff2 + d + 64, sm + bo + 12288 + wb);   // A rows 64-127, chunk 1
    GLDS(pb + boff  + d,      sm + bo + 16384 + wb);   // B chunk 0
    GLDS(pb + boff  + d + 64, sm + bo + 20480 + wb);   // B chunk 1
  };
  const int NIT = KSEL * 2 / 128;      // 48
  stage(0, 0);
  stage(24576, 128);                   // 12 loads in flight
  for (int it = 0; it < NIT; ++it) {
    if (it < NIT - 1) asm volatile("s_waitcnt vmcnt(6)" ::: "memory");
    else              asm volatile("s_waitcnt vmcnt(0)" ::: "memory");
    __builtin_amdgcn_s_barrier();
    __builtin_amdgcn_sched_barrier(0);
    const int cur = (it % 3) * 24576;
    if (it + 2 < NIT) stage(((it + 2) % 3) * 24576, (it + 2) * 128);
    bf16x8 ah[4][2], bh[2][2];
    #pragma unroll
    for (int i = 0; i < 4; ++i) {
      const int ra = (m0 + i * 16) * 64 + fo;
      ah[i][0] = *(const bf16x8*)(sm + cur + 0    + ra);
      ah[i][1] = *(const bf16x8*)(sm + cur + 8192 + ra);
    }
    #pragma unroll
    for (int i = 0; i < 2; ++i) {
      const int rb = (n0 + i * 16) * 64 + fo;
      bh[i][0] = *(const bf16x8*)(sm + cur + 16384 + rb);
      bh[i][1] = *(const bf16x8*)(sm + cur + 20480 + rb);
    }
    #pragma unroll
    for (int c = 0; c < 2; ++c)
      #pragma unroll
      for (int mi = 0; mi < 4; ++mi)
        #pragma unroll
        for (int ni = 0; ni < 2; ++ni)
          acc[mi][ni] = MFMA(ah[mi][c], bh[ni][c], acc[mi][ni]);
  }
  const int rowg = lane >> 4, colc = lane & 15;
  #pragma unroll
  for (int mi = 0; mi < 4; ++mi)
    #pragma unroll
    for (int ni = 0; ni < 2; ++ni) {
      const int m = t0 + m0 + mi * 16 + rowg * 4;
      const int e = e0 + n0 + ni * 16 + colc;
      const size_t base = ((size_t)(b * TLEN + m)) * N_EMBD + e;
      #pragma unroll
      for (int jj = 0; jj < 4; ++jj)
        out[base + (size_t)jj * N_EMBD] = acc[mi][ni][jj];
    }
}

// ---------------- launch ----------------
extern "C" void kernel_launch(void* const* d_in, const int* in_sizes, int n_in,
                              void* d_out, int out_size, void* d_ws, size_t ws_size,
                              hipStream_t stream) {
  const float* x      = (const float*)d_in[0];
  const float* w1     = (const float*)d_in[1];
  const float* w2     = (const float*)d_in[2];
  const float* w_mfc  = (const float*)d_in[3];
  const float* w_proj = (const float*)d_in[4];
  float* out = (float*)d_out;

  char* ws = (char*)d_ws;
  size_t off = 0;
  auto alloc = [&](size_t bytes) -> void* {
    void* p = ws + off;
    off += (bytes + 255) & ~(size_t)255;
    return p;
  };
  const size_t NX  = (size_t)BATCH * TLEN * N_EMBD;   // 6,291,456
  const size_t NW  = (size_t)FULL * N_EMBD;           // 9,437,184
  const size_t NWP = (size_t)BATCH * N_EMBD * KSEL;   // 18,874,368
  const size_t NH  = (size_t)BATCH * TLEN * KSEL;     // 25,165,824

  float* partial = (float*)alloc((size_t)BATCH * 16 * N_EMBD * 4);
  float* hid     = (float*)alloc((size_t)BATCH * HID * 4);
  float* ckbuf   = (float*)alloc((size_t)BATCH * FULL * 4);
  int*   sel     = (int*)  alloc((size_t)BATCH * KSEL * 4);
  unsigned short* xh  = (unsigned short*)alloc(NX * 2);
  unsigned short* wh  = (unsigned short*)alloc(NW * 2);
  unsigned short* wph = (unsigned short*)alloc(NWP * 2);
  unsigned short* hh  = (unsigned short*)alloc(NH * 2);

  // x: round to bf16 + partial pool in one pass (per-d t-order identical to prior rounds)
  split_pool_x<<<dim3(16, BATCH, 3), 64, 0, stream>>>(x, xh, partial);
  // w_mfc round to bf16 (independent)
  round_w_kernel<<<(int)(NW / 4 / 256), 256, 0, stream>>>(w_mfc, wh, (int)(NW / 4));
  // control path (exact fp32, FP-order-identical to prior rounds -> same sel)
  control1_kernel<<<BATCH, 256, 0, stream>>>(partial, w1, hid);
  control2_kernel<<<dim3(FULL / 256, BATCH), 256, 0, stream>>>(hid, w2, ckbuf);
  topk_kernel<<<BATCH, 256, 0, stream>>>(ckbuf, sel);
  // per-batch compacted w_proj operand (bf16), single pass over w_proj
  gather_wp_kernel<<<768, 256, 0, stream>>>(w_proj, sel, wph);
  // sparse heavy path on MFMA (counted-vmcnt pipelines)
  gemm1_mfma<<<dim3(TLEN / 128, KSEL / 128, BATCH), 256, 0, stream>>>(xh, wh, sel, hh);
  gemm2_mfma<<<768, 256, 0, stream>>>(hh, wph, out);
}

// Round 9
// 321.259 us; speedup vs baseline: 4.0204x; 1.0068x over previous
//
#include <hip/hip_runtime.h>

#define N_EMBD 768
#define FULL   12288
#define KSEL   3072
#define BATCH  8
#define TLEN   1024
#define HID    48

typedef short bf16x8 __attribute__((ext_vector_type(8)));
typedef float f32x4 __attribute__((ext_vector_type(4)));
typedef unsigned short u16x4 __attribute__((ext_vector_type(4)));
typedef unsigned short u16x8 __attribute__((ext_vector_type(8)));

#define MFMA(a, b, c) __builtin_amdgcn_mfma_f32_16x16x32_bf16((a), (b), (c), 0, 0, 0)
#define GLDS(g, l) __builtin_amdgcn_global_load_lds( \
    (const __attribute__((address_space(1))) void*)(const void*)(g), \
    (__attribute__((address_space(3))) void*)(void*)(l), 16, 0, 0)

__device__ __forceinline__ unsigned short f2bf(float f) {
  unsigned u = __float_as_uint(f);
  u += 0x7fffu + ((u >> 16) & 1u);   // round-to-nearest-even
  return (unsigned short)(u >> 16);
}
__device__ __forceinline__ float bf2f(unsigned short h) {
  return __uint_as_float(((unsigned)h) << 16);
}

// ---------------- prep: {round x + partial pool} U {round w_mfc}, one dispatch ----------------
// blocks 0..127: (s,b) split_pool with 192 threads; per-(s,d) ascending-t sum order
// identical to all prior rounds -> bit-identical partial -> identical sel.
// blocks 128..703: w_mfc fp32->bf16 (576 blocks x 256 thr x 16 float4).
__global__ __launch_bounds__(256) void prep_kernel(
    const float* __restrict__ x, unsigned short* __restrict__ xh, float* __restrict__ partial,
    const float* __restrict__ w_mfc, unsigned short* __restrict__ wh) {
  if (blockIdx.x < 128) {
    const int s = blockIdx.x & 15;       // t-chunk of 64
    const int b = blockIdx.x >> 4;
    const int tid = threadIdx.x;
    if (tid < 192) {
      const int d = tid * 4;
      const float* base = x + ((size_t)(b * TLEN + s * 64)) * N_EMBD + d;
      float4 sum = {0.f, 0.f, 0.f, 0.f};
      for (int t = 0; t < 64; ++t) {
        const float4 v = *(const float4*)(base + (size_t)t * N_EMBD);
        sum.x += v.x; sum.y += v.y; sum.z += v.z; sum.w += v.w;
        u16x4 h;
        h.x = f2bf(v.x); h.y = f2bf(v.y); h.z = f2bf(v.z); h.w = f2bf(v.w);
        *(u16x4*)(xh + ((size_t)(b * TLEN + s * 64 + t)) * N_EMBD + d) = h;
      }
      float* pp = partial + (b * 16 + s) * N_EMBD + d;
      pp[0] = sum.x; pp[1] = sum.y; pp[2] = sum.z; pp[3] = sum.w;
    }
  } else {
    const int blk = blockIdx.x - 128;    // 0..575
    #pragma unroll
    for (int i = 0; i < 16; ++i) {
      const int idx = (blk * 16 + i) * 256 + threadIdx.x;   // coalesced
      const float4 v = ((const float4*)w_mfc)[idx];
      u16x4 h;
      h.x = f2bf(v.x); h.y = f2bf(v.y); h.z = f2bf(v.z); h.w = f2bf(v.w);
      ((u16x4*)wh)[idx] = h;
    }
  }
}

// ---------------- control1 (fused pool_final): hid[b][i] = relu(dot(pooled[b], w1[i])) ----
__global__ __launch_bounds__(256) void control1_kernel(
    const float* __restrict__ partial, const float* __restrict__ w1, float* __restrict__ hid) {
  __shared__ float w1s[HID][385];   // 73.9 KB
  __shared__ float ps[N_EMBD];
  const int b = blockIdx.x;
  const int tid = threadIdx.x;
  for (int d = tid; d < N_EMBD; d += 256) {
    float sum = 0.f;
    #pragma unroll
    for (int s = 0; s < 16; ++s) sum += partial[(b * 16 + s) * N_EMBD + d];
    ps[d] = sum * (1.f / TLEN);
  }
  float acc = 0.f;
  #pragma unroll
  for (int half = 0; half < 2; ++half) {
    __syncthreads();                 // guards ps (half 0) and w1s reuse (half 1)
    for (int i = tid; i < HID * 384; i += 256) {
      const int r = i / 384, c = i % 384;
      w1s[r][c] = w1[r * N_EMBD + half * 384 + c];
    }
    __syncthreads();
    if (tid < HID) {
      const float* pr = ps + half * 384;
      #pragma unroll 8
      for (int d2 = 0; d2 < 384; ++d2) acc = fmaf(pr[d2], w1s[tid][d2], acc);
    }
  }
  if (tid < HID) hid[b * HID + tid] = fmaxf(acc, 0.f);
}

// ---------------- control2: ck[b][f] = dot(hid[b], w2[f]) ----------------
__global__ void control2_kernel(const float* __restrict__ hid, const float* __restrict__ w2,
                                float* __restrict__ ck) {
  const int b = blockIdx.y;
  const int f = blockIdx.x * 256 + threadIdx.x;
  __shared__ float hid_s[HID];
  if (threadIdx.x < HID) hid_s[threadIdx.x] = hid[b * HID + threadIdx.x];
  __syncthreads();
  const float* wr = w2 + (size_t)f * HID;
  float acc = 0.f;
  #pragma unroll
  for (int j = 0; j < HID; ++j) acc = fmaf(hid_s[j], wr[j], acc);
  ck[b * FULL + f] = acc;
}

// ---------------- top-K selection (radix select, keys in registers) ----------------
__global__ void topk_kernel(const float* __restrict__ ck, int* __restrict__ sel) {
  const int b = blockIdx.x;
  const int tid = threadIdx.x;               // 256
  const int lane = tid & 63, wv = tid >> 6;
  unsigned key[48];
  const int f_lo = tid * 48;
  #pragma unroll
  for (int i = 0; i < 48; ++i) {
    unsigned u = __float_as_uint(ck[b * FULL + f_lo + i]);
    key[i] = (u & 0x80000000u) ? ~u : (u | 0x80000000u);  // order-preserving map
  }
  __shared__ unsigned redw[4];
  __shared__ int sg[257], se[257];
  unsigned prefix = 0;
  int remaining = KSEL;
  for (int bit = 31; bit >= 0; --bit) {
    const unsigned want = prefix | (1u << bit);
    const unsigned shifted = want >> bit;
    int cnt = 0;
    #pragma unroll
    for (int i = 0; i < 48; ++i) cnt += ((key[i] >> bit) == shifted) ? 1 : 0;
    #pragma unroll
    for (int off = 1; off < 64; off <<= 1) cnt += __shfl_xor(cnt, off, 64);
    if (lane == 0) redw[wv] = (unsigned)cnt;
    __syncthreads();
    const int c = (int)(redw[0] + redw[1] + redw[2] + redw[3]);
    __syncthreads();
    if (c >= remaining) prefix = want;
    else remaining -= c;
  }
  const unsigned kth = prefix;
  int cg = 0, ce = 0;
  #pragma unroll
  for (int i = 0; i < 48; ++i) { cg += (key[i] > kth) ? 1 : 0; ce += (key[i] == kth) ? 1 : 0; }
  sg[tid] = cg; se[tid] = ce;
  __syncthreads();
  if (tid == 0) {
    int ag = 0, ae = 0;
    for (int i = 0; i < 256; ++i) {
      int tg = sg[i], te = se[i];
      sg[i] = ag; se[i] = ae;
      ag += tg; ae += te;
    }
    sg[256] = ag;
  }
  __syncthreads();
  const int ng = sg[256];
  int gpos = sg[tid], epos = se[tid];
  #pragma unroll
  for (int i = 0; i < 48; ++i) {
    const unsigned k = key[i];
    const int f = f_lo + i;
    if (k > kth) {
      sel[b * KSEL + (gpos++)] = f;
    } else if (k == kth) {
      const int p = ng + epos;
      if (p < KSEL) sel[b * KSEL + p] = f;
      ++epos;
    }
  }
}

// ---------------- gather w_proj -> wp[b][e][kk] bf16, ONE pass over w_proj ----------------
__global__ __launch_bounds__(256) void gather_wp_kernel(
    const float* __restrict__ wproj, const int* __restrict__ sel,
    unsigned short* __restrict__ wph) {
  __shared__ unsigned short row_s[FULL];   // 24.6 KB
  const int e = blockIdx.x;                // 0..767
  const int tid = threadIdx.x;
  const float* wr = wproj + (size_t)e * FULL;
  #pragma unroll
  for (int i = 0; i < FULL / 4 / 256; ++i) {   // 12 float4 per thread
    const int idx = tid + i * 256;
    const float4 v = ((const float4*)wr)[idx];
    u16x4 h;
    h.x = f2bf(v.x); h.y = f2bf(v.y); h.z = f2bf(v.z); h.w = f2bf(v.w);
    *(u16x4*)(row_s + idx * 4) = h;
  }
  __syncthreads();
  #pragma unroll
  for (int i = 0; i < 12; ++i) {
    const int idx = tid + i * 256;
    const int b = idx / 384, c = idx % 384;
    const int* sp = sel + b * KSEL + c * 8;
    const int4 s0 = ((const int4*)sp)[0];
    const int4 s1 = ((const int4*)sp)[1];
    u16x8 v;
    v[0] = row_s[s0.x]; v[1] = row_s[s0.y]; v[2] = row_s[s0.z]; v[3] = row_s[s0.w];
    v[4] = row_s[s1.x]; v[5] = row_s[s1.y]; v[6] = row_s[s1.z]; v[7] = row_s[s1.w];
    *(u16x8*)(wph + ((size_t)(b * N_EMBD + e)) * KSEL + c * 8) = v;
  }
}

// ---------------- GEMM1 (1-product bf16, 3-buffer counted-vmcnt pipeline) ----------------
// h = relu(xh @ gather(wh, sel)^T). 128x128 tile, BK=32, 4 waves (2x2 of 64x64).
// 48KB LDS = 3 x {A 8K | B 8K}; depth-2 prefetch; vmcnt(4) steady.
__global__ __launch_bounds__(256) void gemm1_mfma(
    const unsigned short* __restrict__ xh, const unsigned short* __restrict__ wh,
    const int* __restrict__ sel, unsigned short* __restrict__ hh) {
  __shared__ __align__(16) char sm[49152];
  const int nx = TLEN / 128, ny = KSEL / 128;          // 8, 24
  const int nwg = nx * ny * BATCH;                     // 1536 (divisible by 8)
  int lin = blockIdx.x + nx * (blockIdx.y + ny * blockIdx.z);
  int swz = (lin & 7) * (nwg >> 3) + (lin >> 3);       // XCD-contiguous chunks
  const int bx = swz % nx; int tmp = swz / nx;
  const int by = tmp % ny; const int b = tmp / ny;
  const int t0 = bx * 128, f0 = by * 128;

  const int tid = threadIdx.x;
  const int wv = tid >> 6, lane = tid & 63;
  const int srow = tid >> 2, sslot = tid & 3;
  const int wb = wv * 1024;

  const char* pxh = (const char*)xh;
  const char* pwh = (const char*)wh;
  const size_t aoff  = ((size_t)(b * TLEN + t0 + srow)) * 1536 + sslot * 16;  // row stride 768*2B
  const size_t aoff2 = aoff + (size_t)64 * 1536;
  const int* selb = sel + b * KSEL;
  const size_t boff  = (size_t)selb[f0 + srow] * 1536 + sslot * 16;
  const size_t boff2 = (size_t)selb[f0 + srow + 64] * 1536 + sslot * 16;

  const int fr = lane & 15, kg = lane >> 4;
  const int fo = fr * 64 + kg * 16;
  const int m0 = (wv >> 1) * 64, n0 = (wv & 1) * 64;

  f32x4 acc[4][4];
  const f32x4 z4 = {0.f, 0.f, 0.f, 0.f};
  #pragma unroll
  for (int mi = 0; mi < 4; ++mi)
    #pragma unroll
    for (int ni = 0; ni < 4; ++ni) acc[mi][ni] = z4;

  auto stage = [&](int bo, int kb) {   // kb = K-chunk byte offset (64B per BK=32)
    GLDS(pxh + aoff  + kb, sm + bo + 0     + wb);
    GLDS(pxh + aoff2 + kb, sm + bo + 4096  + wb);
    GLDS(pwh + boff  + kb, sm + bo + 8192  + wb);
    GLDS(pwh + boff2 + kb, sm + bo + 12288 + wb);
  };
  const int NIT = N_EMBD * 2 / 64;   // 24
  stage(0, 0);
  stage(16384, 64);                  // 8 loads in flight
  for (int it = 0; it < NIT; ++it) {
    if (it < NIT - 1) asm volatile("s_waitcnt vmcnt(4)" ::: "memory");
    else              asm volatile("s_waitcnt vmcnt(0)" ::: "memory");
    __builtin_amdgcn_s_barrier();          // buf cur complete for all waves
    __builtin_amdgcn_sched_barrier(0);
    const int cur = (it % 3) << 14;
    if (it + 2 < NIT) stage(((it + 2) % 3) << 14, (it + 2) * 64);
    bf16x8 ah[4], bh[4];
    #pragma unroll
    for (int i = 0; i < 4; ++i) {
      ah[i] = *(const bf16x8*)(sm + cur + 0    + (m0 + i * 16) * 64 + fo);
      bh[i] = *(const bf16x8*)(sm + cur + 8192 + (n0 + i * 16) * 64 + fo);
    }
    #pragma unroll
    for (int mi = 0; mi < 4; ++mi)
      #pragma unroll
      for (int ni = 0; ni < 4; ++ni)
        acc[mi][ni] = MFMA(ah[mi], bh[ni], acc[mi][ni]);
  }
  __syncthreads();   // all reads retired before sm reuse below
  // epilogue: relu -> bf16, repack through LDS, coalesced 16B stores.
  unsigned short* lh = (unsigned short*)sm;  // [128][128] bf16 = 32KB
  const int rowg = lane >> 4, colc = lane & 15;
  #pragma unroll
  for (int mi = 0; mi < 4; ++mi)
    #pragma unroll
    for (int ni = 0; ni < 4; ++ni) {
      const int row = m0 + mi * 16 + rowg * 4;
      const int col = n0 + ni * 16 + colc;
      #pragma unroll
      for (int j = 0; j < 4; ++j)
        lh[(row + j) * 128 + col] = f2bf(fmaxf(acc[mi][ni][j], 0.f));
    }
  __syncthreads();
  const int orow = tid >> 4, oc = tid & 15;
  #pragma unroll
  for (int i2 = 0; i2 < 8; ++i2) {
    const int row = orow + i2 * 16;
    const u16x8 v = *(const u16x8*)&lh[row * 128 + oc * 8];
    *(u16x8*)(hh + ((size_t)(b * TLEN + t0 + row)) * KSEL + f0 + oc * 8) = v;
  }
}

// ---------------- GEMM2 (1-product, BK=32, 3x12KB counted-vmcnt, 4 blocks/CU) --------
// out = hh @ wph^T. 128x64 tile, 4 waves (2x2 of 64x32), 768 blocks, b->XCD affinity.
// 36KB LDS = 3 x {A 8K | B 4K}; vmcnt(3) steady. Ascending-K accumulation order
// identical to round 8 (each acc gets one MFMA per 32-k step) -> bit-identical out.
__global__ __launch_bounds__(256) void gemm2_mfma(
    const unsigned short* __restrict__ hh, const unsigned short* __restrict__ wph,
    float* __restrict__ out) {
  __shared__ __align__(16) char sm[36864];
  const int lin = blockIdx.x;          // 0..767
  const int b = lin & 7;
  const int j = lin >> 3;              // 0..95
  const int bx = j & 7, by = j >> 3;   // bx 0..7 (t-tile), by 0..11 (e-tile)
  const int t0 = bx * 128, e0 = by * 64;

  const int tid = threadIdx.x;
  const int wv = tid >> 6, lane = tid & 63;
  const int wb = wv * 1024;

  const char* pa = (const char*)hh;
  const char* pb = (const char*)wph;
  const size_t aoff  = ((size_t)(b * TLEN + t0 + (tid >> 2))) * 6144 + (tid & 3) * 16;
  const size_t aoff2 = aoff + (size_t)64 * 6144;
  const size_t boff  = ((size_t)(b * N_EMBD + e0 + (tid >> 2))) * 6144 + (tid & 3) * 16;

  const int fr = lane & 15, kg = lane >> 4;
  const int fo = fr * 64 + kg * 16;
  const int m0 = (wv >> 1) * 64, n0 = (wv & 1) * 32;

  f32x4 acc[4][2];
  const f32x4 z4 = {0.f, 0.f, 0.f, 0.f};
  #pragma unroll
  for (int mi = 0; mi < 4; ++mi)
    #pragma unroll
    for (int ni = 0; ni < 2; ++ni) acc[mi][ni] = z4;

  auto stage = [&](int bo, int d) {    // d = K-chunk byte offset (64B per BK=32)
    GLDS(pa + aoff  + d, sm + bo + 0    + wb);   // A rows 0-63
    GLDS(pa + aoff2 + d, sm + bo + 4096 + wb);   // A rows 64-127
    GLDS(pb + boff  + d, sm + bo + 8192 + wb);   // B rows 0-63
  };
  const int NIT = KSEL / 32;           // 96
  stage(0, 0);
  stage(12288, 64);                    // 6 loads in flight
  for (int it = 0; it < NIT; ++it) {
    if (it < NIT - 1) asm volatile("s_waitcnt vmcnt(3)" ::: "memory");
    else              asm volatile("s_waitcnt vmcnt(0)" ::: "memory");
    __builtin_amdgcn_s_barrier();
    __builtin_amdgcn_sched_barrier(0);
    const int cur = (it % 3) * 12288;
    if (it + 2 < NIT) stage(((it + 2) % 3) * 12288, (it + 2) * 64);
    bf16x8 ah[4], bh[2];
    #pragma unroll
    for (int i = 0; i < 4; ++i)
      ah[i] = *(const bf16x8*)(sm + cur + 0    + (m0 + i * 16) * 64 + fo);
    #pragma unroll
    for (int i = 0; i < 2; ++i)
      bh[i] = *(const bf16x8*)(sm + cur + 8192 + (n0 + i * 16) * 64 + fo);
    #pragma unroll
    for (int mi = 0; mi < 4; ++mi)
      #pragma unroll
      for (int ni = 0; ni < 2; ++ni)
        acc[mi][ni] = MFMA(ah[mi], bh[ni], acc[mi][ni]);
  }
  const int rowg = lane >> 4, colc = lane & 15;
  #pragma unroll
  for (int mi = 0; mi < 4; ++mi)
    #pragma unroll
    for (int ni = 0; ni < 2; ++ni) {
      const int m = t0 + m0 + mi * 16 + rowg * 4;
      const int e = e0 + n0 + ni * 16 + colc;
      const size_t base = ((size_t)(b * TLEN + m)) * N_EMBD + e;
      #pragma unroll
      for (int jj = 0; jj < 4; ++jj)
        out[base + (size_t)jj * N_EMBD] = acc[mi][ni][jj];
    }
}

// ---------------- launch ----------------
extern "C" void kernel_launch(void* const* d_in, const int* in_sizes, int n_in,
                              void* d_out, int out_size, void* d_ws, size_t ws_size,
                              hipStream_t stream) {
  const float* x      = (const float*)d_in[0];
  const float* w1     = (const float*)d_in[1];
  const float* w2     = (const float*)d_in[2];
  const float* w_mfc  = (const float*)d_in[3];
  const float* w_proj = (const float*)d_in[4];
  float* out = (float*)d_out;

  char* ws = (char*)d_ws;
  size_t off = 0;
  auto alloc = [&](size_t bytes) -> void* {
    void* p = ws + off;
    off += (bytes + 255) & ~(size_t)255;
    return p;
  };
  const size_t NX  = (size_t)BATCH * TLEN * N_EMBD;   // 6,291,456
  const size_t NW  = (size_t)FULL * N_EMBD;           // 9,437,184
  const size_t NWP = (size_t)BATCH * N_EMBD * KSEL;   // 18,874,368
  const size_t NH  = (size_t)BATCH * TLEN * KSEL;     // 25,165,824

  float* partial = (float*)alloc((size_t)BATCH * 16 * N_EMBD * 4);
  float* hid     = (float*)alloc((size_t)BATCH * HID * 4);
  float* ckbuf   = (float*)alloc((size_t)BATCH * FULL * 4);
  int*   sel     = (int*)  alloc((size_t)BATCH * KSEL * 4);
  unsigned short* xh  = (unsigned short*)alloc(NX * 2);
  unsigned short* wh  = (unsigned short*)alloc(NW * 2);
  unsigned short* wph = (unsigned short*)alloc(NWP * 2);
  unsigned short* hh  = (unsigned short*)alloc(NH * 2);

  // fused prep: x->bf16 + partial pool  ||  w_mfc->bf16
  prep_kernel<<<704, 256, 0, stream>>>(x, xh, partial, w_mfc, wh);
  // control path (exact fp32, FP-order-identical to prior rounds -> same sel)
  control1_kernel<<<BATCH, 256, 0, stream>>>(partial, w1, hid);
  control2_kernel<<<dim3(FULL / 256, BATCH), 256, 0, stream>>>(hid, w2, ckbuf);
  topk_kernel<<<BATCH, 256, 0, stream>>>(ckbuf, sel);
  // per-batch compacted w_proj operand (bf16), single pass over w_proj
  gather_wp_kernel<<<768, 256, 0, stream>>>(w_proj, sel, wph);
  // sparse heavy path on MFMA (counted-vmcnt pipelines)
  gemm1_mfma<<<dim3(TLEN / 128, KSEL / 128, BATCH), 256, 0, stream>>>(xh, wh, sel, hh);
  gemm2_mfma<<<768, 256, 0, stream>>>(hh, wph, out);
}